// Round 2
// baseline (439.294 us; speedup 1.0000x reference)
//
#include <hip/hip_runtime.h>
#include <math.h>

#define N_NODES 8192
#define EDIM    256
#define HEADS   8
#define HDIM    32
#define NEDGE   262144
#define SCALING 0.17677669529663687f   // 1/sqrt(32)

// ---------------------------------------------------------------------------
// K2: Wksum[d,c] = sum_h W_in[256 + h*32 + d, c];  bksum[d] = sum_h b_in[...]
// ---------------------------------------------------------------------------
__global__ void wksum_kernel(const float* __restrict__ W_in,
                             const float* __restrict__ b_in,
                             float* __restrict__ Wksum,
                             float* __restrict__ bksum) {
    int idx = blockIdx.x * 256 + threadIdx.x;   // 8192 = 32*256
    int d = idx >> 8, c = idx & 255;
    float sum = 0.f;
    for (int h = 0; h < HEADS; ++h)
        sum += W_in[(size_t)(EDIM + h * HDIM + d) * EDIM + c];
    Wksum[idx] = sum;
    if (c == 0) {
        float bs = 0.f;
        for (int h = 0; h < HEADS; ++h)
            bs += b_in[EDIM + h * HDIM + d];
        bksum[d] = bs;
    }
}

// ---------------------------------------------------------------------------
// K1: tiled f32 GEMM: out[n, j] = query[n,:] . Wsel[j,:]  (j in [0,288))
// ---------------------------------------------------------------------------
__global__ __launch_bounds__(256) void qk_gemm(const float* __restrict__ query,
                                               const float* __restrict__ W_in,
                                               const float* __restrict__ b_in,
                                               const float* __restrict__ Wksum,
                                               const float* __restrict__ bksum,
                                               float* __restrict__ q_out,
                                               float* __restrict__ khs_out) {
    __shared__ float As[64][17];
    __shared__ float Bs[16][65];

    int row0 = blockIdx.x * 64;
    int j0   = blockIdx.y * 64;
    int t    = threadIdx.x;
    int tx = t & 15, ty = t >> 4;

    float acc[4][4];
#pragma unroll
    for (int i = 0; i < 4; ++i)
#pragma unroll
        for (int j = 0; j < 4; ++j) acc[i][j] = 0.f;

    int lm  = t >> 2;          // 0..63 row (A) / j (B)
    int lk4 = (t & 3) * 4;     // 0,4,8,12

    for (int k0 = 0; k0 < EDIM; k0 += 16) {
        {
            const float4 a = *(const float4*)(query + (size_t)(row0 + lm) * EDIM + k0 + lk4);
            As[lm][lk4 + 0] = a.x; As[lm][lk4 + 1] = a.y;
            As[lm][lk4 + 2] = a.z; As[lm][lk4 + 3] = a.w;
        }
        {
            int jglob = j0 + lm;
            float4 b = make_float4(0.f, 0.f, 0.f, 0.f);
            if (jglob < 288) {
                const float* wrow = (jglob < 256)
                    ? (W_in + (size_t)jglob * EDIM)
                    : (Wksum + (size_t)(jglob - 256) * EDIM);
                b = *(const float4*)(wrow + k0 + lk4);
            }
            Bs[lk4 + 0][lm] = b.x; Bs[lk4 + 1][lm] = b.y;
            Bs[lk4 + 2][lm] = b.z; Bs[lk4 + 3][lm] = b.w;
        }
        __syncthreads();
#pragma unroll
        for (int kk = 0; kk < 16; ++kk) {
            float a[4], b[4];
#pragma unroll
            for (int i = 0; i < 4; ++i) a[i] = As[ty * 4 + i][kk];
#pragma unroll
            for (int j = 0; j < 4; ++j) b[j] = Bs[kk][tx * 4 + j];
#pragma unroll
            for (int i = 0; i < 4; ++i)
#pragma unroll
                for (int j = 0; j < 4; ++j)
                    acc[i][j] = fmaf(a[i], b[j], acc[i][j]);
        }
        __syncthreads();
    }

#pragma unroll
    for (int i = 0; i < 4; ++i) {
        int row = row0 + ty * 4 + i;
#pragma unroll
        for (int j = 0; j < 4; ++j) {
            int jglob = j0 + tx * 4 + j;
            if (jglob < 256) {
                q_out[(size_t)row * EDIM + jglob] = (acc[i][j] + b_in[jglob]) * SCALING;
            } else if (jglob < 288) {
                int d = jglob - 256;
                khs_out[(size_t)row * HDIM + d] = acc[i][j] + bksum[d];
            }
        }
    }
}

// ---------------------------------------------------------------------------
// K3a: histogram of dst
// ---------------------------------------------------------------------------
__global__ __launch_bounds__(256) void hist_kernel(const int* __restrict__ edge_index,
                                                   int* __restrict__ counts) {
    int e = blockIdx.x * 256 + threadIdx.x;
    atomicAdd(counts + edge_index[NEDGE + e], 1);
}

// ---------------------------------------------------------------------------
// K3b: exclusive prefix scan of counts[8192] -> offsets[8193], cursor copy
// single block, 256 threads, 32 bins/thread
// ---------------------------------------------------------------------------
__global__ __launch_bounds__(256) void scan_kernel(const int* __restrict__ counts,
                                                   int* __restrict__ offsets,
                                                   int* __restrict__ cursor) {
    __shared__ int part[256];
    int t = threadIdx.x;
    int base = t * 32;
    int local[32];
    int s = 0;
#pragma unroll
    for (int i = 0; i < 32; ++i) { local[i] = counts[base + i]; s += local[i]; }
    part[t] = s;
    __syncthreads();
    for (int st = 1; st < 256; st <<= 1) {
        int v = (t >= st) ? part[t - st] : 0;
        __syncthreads();
        part[t] += v;
        __syncthreads();
    }
    int off = part[t] - s;   // exclusive
#pragma unroll
    for (int i = 0; i < 32; ++i) {
        offsets[base + i] = off;
        cursor[base + i]  = off;
        off += local[i];
    }
    if (t == 255) offsets[8192] = off;
}

// ---------------------------------------------------------------------------
// K3c: scatter edges into dst-grouped order; stream bias segment-sum into col;
//      mark touched.
// ---------------------------------------------------------------------------
__global__ __launch_bounds__(256) void scatter_kernel(const int* __restrict__ edge_index,
                                                      const float* __restrict__ bias,
                                                      int* __restrict__ cursor,
                                                      int* __restrict__ sorted_src,
                                                      int* __restrict__ touched,
                                                      float* __restrict__ col) {
    int e = blockIdx.x * 256 + threadIdx.x;
    int src = edge_index[e];
    int dst = edge_index[NEDGE + e];
    int pos = atomicAdd(cursor + dst, 1);
    sorted_src[pos] = src;
    touched[src] = 1;
#pragma unroll
    for (int h = 0; h < HEADS; ++h)
        atomicAdd(col + (size_t)h * N_NODES + src, bias[(size_t)h * NEDGE + e]);
}

// ---------------------------------------------------------------------------
// K3d: dst-grouped edge dot. One wave per dst node.
//   q[dst] staged in LDS (loaded ONCE per dst); each 8-lane group handles one
//   edge of the group; per head: 4-wide FMA + 3 shfl reduce; lane sub==h keeps
//   head h's value; one 64-lane atomic instr per 8 edges per head-batch.
// ---------------------------------------------------------------------------
__global__ __launch_bounds__(256) void edge_dst_kernel(const float* __restrict__ q,
                                                       const float* __restrict__ khs,
                                                       const int* __restrict__ sorted_src,
                                                       const int* __restrict__ offsets,
                                                       float* __restrict__ col) {
    __shared__ float qs[4][256];
    int wslot = threadIdx.x >> 6;
    int lane  = threadIdx.x & 63;
    int dst   = blockIdx.x * 4 + wslot;

    // stage q[dst] (wave-coherent; no barrier needed)
    *(float4*)(&qs[wslot][lane * 4]) =
        *(const float4*)(q + (size_t)dst * EDIM + lane * 4);

    int start = offsets[dst], end = offsets[dst + 1];
    int grp = lane >> 3, sub = lane & 7;

    for (int b = start + grp; b < end; b += 8) {   // same b for all 8 lanes of grp
        int src = sorted_src[b];
        const float4 kv = *(const float4*)(khs + (size_t)src * HDIM + sub * 4);
        float mine = 0.f;
#pragma unroll
        for (int h = 0; h < HEADS; ++h) {
            const float4 qv = *(const float4*)(&qs[wslot][h * HDIM + sub * 4]);
            float p = kv.x * qv.x + kv.y * qv.y + kv.z * qv.z + kv.w * qv.w;
            p += __shfl_xor(p, 1);
            p += __shfl_xor(p, 2);
            p += __shfl_xor(p, 4);
            if (sub == h) mine = p;
        }
        atomicAdd(col + (size_t)sub * N_NODES + src, mine);
    }
}

// ---------------------------------------------------------------------------
// K4a: per-head softmax over nodes
// ---------------------------------------------------------------------------
__global__ __launch_bounds__(256) void softmax_kernel(const float* __restrict__ col,
                                                      const int* __restrict__ touched,
                                                      float* __restrict__ attn) {
    int h = blockIdx.x;
    const float* c = col + (size_t)h * N_NODES;
    float* a = attn + (size_t)h * N_NODES;
    __shared__ float red[256];
    int t = threadIdx.x;

    float m = -INFINITY;
    for (int n = t; n < N_NODES; n += 256)
        if (touched[n]) m = fmaxf(m, c[n]);
    red[t] = m; __syncthreads();
    for (int st = 128; st; st >>= 1) {
        if (t < st) red[t] = fmaxf(red[t], red[t + st]);
        __syncthreads();
    }
    m = red[0]; __syncthreads();

    float sum = 0.f;
    for (int n = t; n < N_NODES; n += 256) {
        float e = touched[n] ? expf(c[n] - m) : 0.f;
        a[n] = e;
        sum += e;
    }
    red[t] = sum; __syncthreads();
    for (int st = 128; st; st >>= 1) {
        if (t < st) red[t] += red[t + st];
        __syncthreads();
    }
    float inv = 1.f / red[0];
    for (int n = t; n < N_NODES; n += 256)
        a[n] *= inv;
}

// ---------------------------------------------------------------------------
// K4b: s[h, c] = sum_n attn[h,n] * query[n, c]   (skip all-zero node chunks)
// ---------------------------------------------------------------------------
__global__ __launch_bounds__(256) void sweight_kernel(const float* __restrict__ attn,
                                                      const float* __restrict__ query,
                                                      float* __restrict__ s) {
    int h = blockIdx.y;
    int n0 = blockIdx.x * 256;
    int t = threadIdx.x;
    __shared__ float aw[256];
    __shared__ float red[256];

    float w = attn[(size_t)h * N_NODES + n0 + t];
    aw[t] = w;
    red[t] = w;
    __syncthreads();
    for (int st = 128; st; st >>= 1) {
        if (t < st) red[t] = fmaxf(red[t], red[t + st]);
        __syncthreads();
    }
    if (red[0] == 0.f) return;

    float acc = 0.f;
    for (int n = 0; n < 256; ++n) {
        float wn = aw[n];
        if (wn != 0.f)
            acc = fmaf(wn, query[(size_t)(n0 + n) * EDIM + t], acc);
    }
    atomicAdd(s + (size_t)h * EDIM + t, acc);
}

// ---------------------------------------------------------------------------
// K5: two chained 256-GEMVs -> single output row r
// ---------------------------------------------------------------------------
__global__ __launch_bounds__(256) void final_kernel(const float* __restrict__ s,
                                                    const float* __restrict__ W_in,
                                                    const float* __restrict__ b_in,
                                                    const float* __restrict__ W_out,
                                                    const float* __restrict__ b_out,
                                                    float* __restrict__ r) {
    __shared__ float of[256];
    int j = threadIdx.x;
    int h = j >> 5;
    const float* wrow = W_in + (size_t)(2 * EDIM + j) * EDIM;
    const float* sh = s + (size_t)h * EDIM;
    float acc = b_in[2 * EDIM + j];
    for (int c = 0; c < EDIM; ++c) acc = fmaf(sh[c], wrow[c], acc);
    of[j] = acc;
    __syncthreads();
    const float* wo = W_out + (size_t)j * EDIM;
    float acc2 = b_out[j];
    for (int c = 0; c < EDIM; ++c) acc2 = fmaf(wo[c], of[c], acc2);
    r[j] = acc2;
}

// ---------------------------------------------------------------------------
// K6: broadcast row r to all N rows of out.
// ---------------------------------------------------------------------------
__global__ __launch_bounds__(256) void bcast_kernel(const float* __restrict__ r,
                                                    float* __restrict__ out) {
    int idx = blockIdx.x * blockDim.x + threadIdx.x;
    const float4* r4 = (const float4*)r;
    ((float4*)out)[idx] = r4[idx & 63];
}

// ---------------------------------------------------------------------------
extern "C" void kernel_launch(void* const* d_in, const int* in_sizes, int n_in,
                              void* d_out, int out_size, void* d_ws, size_t ws_size,
                              hipStream_t stream) {
    const float* query     = (const float*)d_in[0];
    const int*   edge_idx  = (const int*)d_in[1];
    const float* attn_bias = (const float*)d_in[2];
    const float* W_in      = (const float*)d_in[3];
    const float* b_in      = (const float*)d_in[4];
    const float* W_out     = (const float*)d_in[5];
    const float* b_out     = (const float*)d_in[6];
    float* out = (float*)d_out;
    float* ws  = (float*)d_ws;

    float* q        = ws;                           // 2,097,152
    float* khs      = q + 2097152;                  //   262,144
    float* Wksum    = khs + 262144;                 //     8,192
    float* bksum    = Wksum + 8192;                 //        64
    float* r        = bksum + 64;                   //       256
    // ---- zeroed region starts here ----
    float* col      = r + 256;                      //    65,536
    int*   touched  = (int*)(col + 65536);          //     8,192
    float* attn     = (float*)(touched + 8192);     //    65,536
    float* s        = attn + 65536;                 //     2,048
    int*   counts   = (int*)(s + 2048);             //     8,192
    int*   cursor   = counts + 8192;                //     8,192
    // ---- zeroed region ends here ----
    int*   offsets  = cursor + 8192;                //     8,193
    int*   sorted_src = offsets + 8200;             //   262,144

    // zero: col, touched, attn, s, counts, cursor (contiguous)
    hipMemsetAsync(col, 0,
                   (size_t)(65536 + 8192 + 65536 + 2048 + 8192 + 8192) * 4,
                   stream);

    wksum_kernel<<<32, 256, 0, stream>>>(W_in, b_in, Wksum, bksum);

    dim3 g1(N_NODES / 64, 5);
    qk_gemm<<<g1, 256, 0, stream>>>(query, W_in, b_in, Wksum, bksum, q, khs);

    hist_kernel<<<NEDGE / 256, 256, 0, stream>>>(edge_idx, counts);
    scan_kernel<<<1, 256, 0, stream>>>(counts, offsets, cursor);
    scatter_kernel<<<NEDGE / 256, 256, 0, stream>>>(edge_idx, attn_bias, cursor,
                                                    sorted_src, touched, col);
    edge_dst_kernel<<<N_NODES / 4, 256, 0, stream>>>(q, khs, sorted_src, offsets, col);

    softmax_kernel<<<HEADS, 256, 0, stream>>>(col, touched, attn);

    dim3 g4(N_NODES / 256, HEADS);
    sweight_kernel<<<g4, 256, 0, stream>>>(attn, query, s);

    final_kernel<<<1, 256, 0, stream>>>(s, W_in, b_in, W_out, b_out, r);

    bcast_kernel<<<(N_NODES * EDIM / 4) / 256, 256, 0, stream>>>(r, out);
}

// Round 3
// 268.048 us; speedup vs baseline: 1.6389x; 1.6389x over previous
//
#include <hip/hip_runtime.h>
#include <math.h>

#define N_NODES 8192
#define EDIM    256
#define HEADS   8
#define HDIM    32
#define NEDGE   262144
#define SCALING 0.17677669529663687f   // 1/sqrt(32)

// ---------------------------------------------------------------------------
// K2: Wksum[d,c] = sum_h W_in[256 + h*32 + d, c];  bksum[d] = sum_h b_in[...]
// ---------------------------------------------------------------------------
__global__ void wksum_kernel(const float* __restrict__ W_in,
                             const float* __restrict__ b_in,
                             float* __restrict__ Wksum,
                             float* __restrict__ bksum) {
    int idx = blockIdx.x * 256 + threadIdx.x;   // 8192 = 32*256
    int d = idx >> 8, c = idx & 255;
    float sum = 0.f;
    for (int h = 0; h < HEADS; ++h)
        sum += W_in[(size_t)(EDIM + h * HDIM + d) * EDIM + c];
    Wksum[idx] = sum;
    if (c == 0) {
        float bs = 0.f;
        for (int h = 0; h < HEADS; ++h)
            bs += b_in[EDIM + h * HDIM + d];
        bksum[d] = bs;
    }
}

// ---------------------------------------------------------------------------
// K1: tiled f32 GEMM: out[n, j] = query[n,:] . Wsel[j,:]  (j in [0,288))
// ---------------------------------------------------------------------------
__global__ __launch_bounds__(256) void qk_gemm(const float* __restrict__ query,
                                               const float* __restrict__ W_in,
                                               const float* __restrict__ b_in,
                                               const float* __restrict__ Wksum,
                                               const float* __restrict__ bksum,
                                               float* __restrict__ q_out,
                                               float* __restrict__ khs_out) {
    __shared__ float As[64][17];
    __shared__ float Bs[16][65];

    int row0 = blockIdx.x * 64;
    int j0   = blockIdx.y * 64;
    int t    = threadIdx.x;
    int tx = t & 15, ty = t >> 4;

    float acc[4][4];
#pragma unroll
    for (int i = 0; i < 4; ++i)
#pragma unroll
        for (int j = 0; j < 4; ++j) acc[i][j] = 0.f;

    int lm  = t >> 2;          // 0..63 row (A) / j (B)
    int lk4 = (t & 3) * 4;     // 0,4,8,12

    for (int k0 = 0; k0 < EDIM; k0 += 16) {
        {
            const float4 a = *(const float4*)(query + (size_t)(row0 + lm) * EDIM + k0 + lk4);
            As[lm][lk4 + 0] = a.x; As[lm][lk4 + 1] = a.y;
            As[lm][lk4 + 2] = a.z; As[lm][lk4 + 3] = a.w;
        }
        {
            int jglob = j0 + lm;
            float4 b = make_float4(0.f, 0.f, 0.f, 0.f);
            if (jglob < 288) {
                const float* wrow = (jglob < 256)
                    ? (W_in + (size_t)jglob * EDIM)
                    : (Wksum + (size_t)(jglob - 256) * EDIM);
                b = *(const float4*)(wrow + k0 + lk4);
            }
            Bs[lk4 + 0][lm] = b.x; Bs[lk4 + 1][lm] = b.y;
            Bs[lk4 + 2][lm] = b.z; Bs[lk4 + 3][lm] = b.w;
        }
        __syncthreads();
#pragma unroll
        for (int kk = 0; kk < 16; ++kk) {
            float a[4], b[4];
#pragma unroll
            for (int i = 0; i < 4; ++i) a[i] = As[ty * 4 + i][kk];
#pragma unroll
            for (int j = 0; j < 4; ++j) b[j] = Bs[kk][tx * 4 + j];
#pragma unroll
            for (int i = 0; i < 4; ++i)
#pragma unroll
                for (int j = 0; j < 4; ++j)
                    acc[i][j] = fmaf(a[i], b[j], acc[i][j]);
        }
        __syncthreads();
    }

#pragma unroll
    for (int i = 0; i < 4; ++i) {
        int row = row0 + ty * 4 + i;
#pragma unroll
        for (int j = 0; j < 4; ++j) {
            int jglob = j0 + tx * 4 + j;
            if (jglob < 256) {
                q_out[(size_t)row * EDIM + jglob] = (acc[i][j] + b_in[jglob]) * SCALING;
            } else if (jglob < 288) {
                int d = jglob - 256;
                khs_out[(size_t)row * HDIM + d] = acc[i][j] + bksum[d];
            }
        }
    }
}

// ---------------------------------------------------------------------------
// K3a: histogram of src
// ---------------------------------------------------------------------------
__global__ __launch_bounds__(256) void hist_kernel(const int* __restrict__ edge_index,
                                                   int* __restrict__ counts) {
    int e = blockIdx.x * 256 + threadIdx.x;
    atomicAdd(counts + edge_index[e], 1);
}

// ---------------------------------------------------------------------------
// K3b: exclusive prefix scan of counts[8192] -> offsets[8193], cursor copy
// ---------------------------------------------------------------------------
__global__ __launch_bounds__(256) void scan_kernel(const int* __restrict__ counts,
                                                   int* __restrict__ offsets,
                                                   int* __restrict__ cursor) {
    __shared__ int part[256];
    int t = threadIdx.x;
    int base = t * 32;
    int local[32];
    int s = 0;
#pragma unroll
    for (int i = 0; i < 32; ++i) { local[i] = counts[base + i]; s += local[i]; }
    part[t] = s;
    __syncthreads();
    for (int st = 1; st < 256; st <<= 1) {
        int v = (t >= st) ? part[t - st] : 0;
        __syncthreads();
        part[t] += v;
        __syncthreads();
    }
    int off = part[t] - s;   // exclusive
#pragma unroll
    for (int i = 0; i < 32; ++i) {
        offsets[base + i] = off;
        cursor[base + i]  = off;
        off += local[i];
    }
    if (t == 255) offsets[8192] = off;
}

// ---------------------------------------------------------------------------
// K3c: scatter edges into src-grouped order (dst and edge-id arrays).
// ---------------------------------------------------------------------------
__global__ __launch_bounds__(256) void scatter_kernel(const int* __restrict__ edge_index,
                                                      int* __restrict__ cursor,
                                                      int* __restrict__ sorted_dst,
                                                      int* __restrict__ sorted_eid) {
    int e = blockIdx.x * 256 + threadIdx.x;
    int src = edge_index[e];
    int dst = edge_index[NEDGE + e];
    int pos = atomicAdd(cursor + src, 1);
    sorted_dst[pos] = dst;
    sorted_eid[pos] = e;
}

// ---------------------------------------------------------------------------
// K3d: per-src segment reduction, NO atomics.
//   col[h,j] = (sum_{e:src=j} q[dst_e,h,:]) . khs[j,:] + sum_{e:src=j} bias[h,e]
// One wave per src node j. Lane l accumulates q components 4l..4l+3
// (head = l>>3, dims (l&7)*4..+3).
// ---------------------------------------------------------------------------
__global__ __launch_bounds__(256) void src_edge_kernel(const float* __restrict__ q,
                                                       const float* __restrict__ khs,
                                                       const float* __restrict__ bias,
                                                       const int* __restrict__ sorted_dst,
                                                       const int* __restrict__ sorted_eid,
                                                       const int* __restrict__ offsets,
                                                       float* __restrict__ col) {
    int wslot = threadIdx.x >> 6;
    int lane  = threadIdx.x & 63;
    int j     = blockIdx.x * 4 + wslot;
    int start = offsets[j], end = offsets[j + 1];
    if (start == end) return;   // untouched node: col never read

    int sub = lane & 7, grp = lane >> 3;
    const float4* q4 = (const float4*)q;

    // --- accumulate q rows of this src's dst neighbors (coalesced gathers) ---
    float4 a0 = make_float4(0.f, 0.f, 0.f, 0.f);
    float4 a1 = make_float4(0.f, 0.f, 0.f, 0.f);
    int p = start;
    for (; p + 1 < end; p += 2) {
        int d0 = sorted_dst[p];
        int d1 = sorted_dst[p + 1];
        float4 v0 = q4[(size_t)d0 * 64 + lane];
        float4 v1 = q4[(size_t)d1 * 64 + lane];
        a0.x += v0.x; a0.y += v0.y; a0.z += v0.z; a0.w += v0.w;
        a1.x += v1.x; a1.y += v1.y; a1.z += v1.z; a1.w += v1.w;
    }
    if (p < end) {
        int d0 = sorted_dst[p];
        float4 v0 = q4[(size_t)d0 * 64 + lane];
        a0.x += v0.x; a0.y += v0.y; a0.z += v0.z; a0.w += v0.w;
    }
    a0.x += a1.x; a0.y += a1.y; a0.z += a1.z; a0.w += a1.w;

    // --- bias segment sum: lane handles head `sub`, positions start+grp, +8 ---
    float ab = 0.f;
    for (int pb = start + grp; pb < end; pb += 8)
        ab += bias[(size_t)sub * NEDGE + sorted_eid[pb]];
    ab += __shfl_xor(ab, 8);
    ab += __shfl_xor(ab, 16);
    ab += __shfl_xor(ab, 32);          // now every lane has bsum for head=sub

    // --- dot with khs[j] ---
    const float4 kv = *(const float4*)(khs + (size_t)j * HDIM + sub * 4);
    float pd = a0.x * kv.x + a0.y * kv.y + a0.z * kv.z + a0.w * kv.w;
    pd += __shfl_xor(pd, 1);
    pd += __shfl_xor(pd, 2);
    pd += __shfl_xor(pd, 4);           // every lane of 8-group has dot for head=grp

    if (grp == sub)                    // lanes 0,9,18,...,63: head h = grp = sub
        col[(size_t)grp * N_NODES + j] = pd + ab;
}

// ---------------------------------------------------------------------------
// K4a: per-head softmax over nodes; touched derived from offsets run length
// ---------------------------------------------------------------------------
__global__ __launch_bounds__(256) void softmax_kernel(const float* __restrict__ col,
                                                      const int* __restrict__ offsets,
                                                      float* __restrict__ attn) {
    int h = blockIdx.x;
    const float* c = col + (size_t)h * N_NODES;
    float* a = attn + (size_t)h * N_NODES;
    __shared__ float red[256];
    int t = threadIdx.x;

    float m = -INFINITY;
    for (int n = t; n < N_NODES; n += 256)
        if (offsets[n + 1] > offsets[n]) m = fmaxf(m, c[n]);
    red[t] = m; __syncthreads();
    for (int st = 128; st; st >>= 1) {
        if (t < st) red[t] = fmaxf(red[t], red[t + st]);
        __syncthreads();
    }
    m = red[0]; __syncthreads();

    float sum = 0.f;
    for (int n = t; n < N_NODES; n += 256) {
        float e = (offsets[n + 1] > offsets[n]) ? expf(c[n] - m) : 0.f;
        a[n] = e;
        sum += e;
    }
    red[t] = sum; __syncthreads();
    for (int st = 128; st; st >>= 1) {
        if (t < st) red[t] += red[t + st];
        __syncthreads();
    }
    float inv = 1.f / red[0];
    for (int n = t; n < N_NODES; n += 256)
        a[n] *= inv;
}

// ---------------------------------------------------------------------------
// K4b: s[h, c] = sum_n attn[h,n] * query[n, c]   (skip all-zero node chunks)
// ---------------------------------------------------------------------------
__global__ __launch_bounds__(256) void sweight_kernel(const float* __restrict__ attn,
                                                      const float* __restrict__ query,
                                                      float* __restrict__ s) {
    int h = blockIdx.y;
    int n0 = blockIdx.x * 256;
    int t = threadIdx.x;
    __shared__ float aw[256];
    __shared__ float red[256];

    float w = attn[(size_t)h * N_NODES + n0 + t];
    aw[t] = w;
    red[t] = w;
    __syncthreads();
    for (int st = 128; st; st >>= 1) {
        if (t < st) red[t] = fmaxf(red[t], red[t + st]);
        __syncthreads();
    }
    if (red[0] == 0.f) return;

    float acc = 0.f;
    for (int n = 0; n < 256; ++n) {
        float wn = aw[n];
        if (wn != 0.f)
            acc = fmaf(wn, query[(size_t)(n0 + n) * EDIM + t], acc);
    }
    atomicAdd(s + (size_t)h * EDIM + t, acc);
}

// ---------------------------------------------------------------------------
// K5: two chained 256-GEMVs -> single output row r
// ---------------------------------------------------------------------------
__global__ __launch_bounds__(256) void final_kernel(const float* __restrict__ s,
                                                    const float* __restrict__ W_in,
                                                    const float* __restrict__ b_in,
                                                    const float* __restrict__ W_out,
                                                    const float* __restrict__ b_out,
                                                    float* __restrict__ r) {
    __shared__ float of[256];
    int j = threadIdx.x;
    int h = j >> 5;
    const float* wrow = W_in + (size_t)(2 * EDIM + j) * EDIM;
    const float* sh = s + (size_t)h * EDIM;
    float acc = b_in[2 * EDIM + j];
    for (int c = 0; c < EDIM; ++c) acc = fmaf(sh[c], wrow[c], acc);
    of[j] = acc;
    __syncthreads();
    const float* wo = W_out + (size_t)j * EDIM;
    float acc2 = b_out[j];
    for (int c = 0; c < EDIM; ++c) acc2 = fmaf(wo[c], of[c], acc2);
    r[j] = acc2;
}

// ---------------------------------------------------------------------------
// K6: broadcast row r to all N rows of out.
// ---------------------------------------------------------------------------
__global__ __launch_bounds__(256) void bcast_kernel(const float* __restrict__ r,
                                                    float* __restrict__ out) {
    int idx = blockIdx.x * blockDim.x + threadIdx.x;
    const float4* r4 = (const float4*)r;
    ((float4*)out)[idx] = r4[idx & 63];
}

// ---------------------------------------------------------------------------
extern "C" void kernel_launch(void* const* d_in, const int* in_sizes, int n_in,
                              void* d_out, int out_size, void* d_ws, size_t ws_size,
                              hipStream_t stream) {
    const float* query     = (const float*)d_in[0];
    const int*   edge_idx  = (const int*)d_in[1];
    const float* attn_bias = (const float*)d_in[2];
    const float* W_in      = (const float*)d_in[3];
    const float* b_in      = (const float*)d_in[4];
    const float* W_out     = (const float*)d_in[5];
    const float* b_out     = (const float*)d_in[6];
    float* out = (float*)d_out;
    float* ws  = (float*)d_ws;

    float* q          = ws;                          // 2,097,152
    float* khs        = q + 2097152;                 //   262,144
    float* Wksum      = khs + 262144;                //     8,192
    float* bksum      = Wksum + 8192;                //        64
    float* r          = bksum + 64;                  //       256
    // ---- zeroed region: s (2048) + counts (8192) ----
    float* s          = r + 256;                     //     2,048
    int*   counts     = (int*)(s + 2048);            //     8,192
    // ---- end zeroed region ----
    int*   cursor     = counts + 8192;               //     8,192
    int*   offsets    = cursor + 8192;               //     8,200 (8193+pad)
    int*   sorted_dst = offsets + 8200;              //   262,144
    int*   sorted_eid = sorted_dst + 262144;         //   262,144
    float* col        = (float*)(sorted_eid + 262144); //  65,536
    float* attn       = col + 65536;                 //    65,536

    hipMemsetAsync(s, 0, (size_t)(2048 + 8192) * 4, stream);

    wksum_kernel<<<32, 256, 0, stream>>>(W_in, b_in, Wksum, bksum);

    dim3 g1(N_NODES / 64, 5);
    qk_gemm<<<g1, 256, 0, stream>>>(query, W_in, b_in, Wksum, bksum, q, khs);

    hist_kernel<<<NEDGE / 256, 256, 0, stream>>>(edge_idx, counts);
    scan_kernel<<<1, 256, 0, stream>>>(counts, offsets, cursor);
    scatter_kernel<<<NEDGE / 256, 256, 0, stream>>>(edge_idx, cursor,
                                                    sorted_dst, sorted_eid);
    src_edge_kernel<<<N_NODES / 4, 256, 0, stream>>>(q, khs, attn_bias,
                                                     sorted_dst, sorted_eid,
                                                     offsets, col);

    softmax_kernel<<<HEADS, 256, 0, stream>>>(col, offsets, attn);

    dim3 g4(N_NODES / 256, HEADS);
    sweight_kernel<<<g4, 256, 0, stream>>>(attn, query, s);

    final_kernel<<<1, 256, 0, stream>>>(s, W_in, b_in, W_out, b_out, r);

    bcast_kernel<<<(N_NODES * EDIM / 4) / 256, 256, 0, stream>>>(r, out);
}

// Round 4
// 206.898 us; speedup vs baseline: 2.1232x; 1.2956x over previous
//
#include <hip/hip_runtime.h>
#include <math.h>

#define N_NODES 8192
#define EDIM    256
#define HEADS   8
#define HDIM    32
#define NEDGE   262144
#define SCALING 0.17677669529663687f   // 1/sqrt(32)
#define SW_CHUNK 32
#define SW_BLOCKS (N_NODES / SW_CHUNK)   // 256

// ---------------------------------------------------------------------------
// K2: Wksum[d,c] = sum_h W_in[256 + h*32 + d, c];  bksum[d] = sum_h b_in[...]
// ---------------------------------------------------------------------------
__global__ void wksum_kernel(const float* __restrict__ W_in,
                             const float* __restrict__ b_in,
                             float* __restrict__ Wksum,
                             float* __restrict__ bksum) {
    int idx = blockIdx.x * 256 + threadIdx.x;   // 8192 = 32*256
    int d = idx >> 8, c = idx & 255;
    float sum = 0.f;
    for (int h = 0; h < HEADS; ++h)
        sum += W_in[(size_t)(EDIM + h * HDIM + d) * EDIM + c];
    Wksum[idx] = sum;
    if (c == 0) {
        float bs = 0.f;
        for (int h = 0; h < HEADS; ++h)
            bs += b_in[EDIM + h * HDIM + d];
        bksum[d] = bs;
    }
}

// ---------------------------------------------------------------------------
// K1: tiled f32 GEMM: out[n, j] = query[n,:] . Wsel[j,:]  (j in [0,288))
// ---------------------------------------------------------------------------
__global__ __launch_bounds__(256) void qk_gemm(const float* __restrict__ query,
                                               const float* __restrict__ W_in,
                                               const float* __restrict__ b_in,
                                               const float* __restrict__ Wksum,
                                               const float* __restrict__ bksum,
                                               float* __restrict__ q_out,
                                               float* __restrict__ khs_out) {
    __shared__ float As[64][17];
    __shared__ float Bs[16][65];

    int row0 = blockIdx.x * 64;
    int j0   = blockIdx.y * 64;
    int t    = threadIdx.x;
    int tx = t & 15, ty = t >> 4;

    float acc[4][4];
#pragma unroll
    for (int i = 0; i < 4; ++i)
#pragma unroll
        for (int j = 0; j < 4; ++j) acc[i][j] = 0.f;

    int lm  = t >> 2;          // 0..63 row (A) / j (B)
    int lk4 = (t & 3) * 4;     // 0,4,8,12

    for (int k0 = 0; k0 < EDIM; k0 += 16) {
        {
            const float4 a = *(const float4*)(query + (size_t)(row0 + lm) * EDIM + k0 + lk4);
            As[lm][lk4 + 0] = a.x; As[lm][lk4 + 1] = a.y;
            As[lm][lk4 + 2] = a.z; As[lm][lk4 + 3] = a.w;
        }
        {
            int jglob = j0 + lm;
            float4 b = make_float4(0.f, 0.f, 0.f, 0.f);
            if (jglob < 288) {
                const float* wrow = (jglob < 256)
                    ? (W_in + (size_t)jglob * EDIM)
                    : (Wksum + (size_t)(jglob - 256) * EDIM);
                b = *(const float4*)(wrow + k0 + lk4);
            }
            Bs[lk4 + 0][lm] = b.x; Bs[lk4 + 1][lm] = b.y;
            Bs[lk4 + 2][lm] = b.z; Bs[lk4 + 3][lm] = b.w;
        }
        __syncthreads();
#pragma unroll
        for (int kk = 0; kk < 16; ++kk) {
            float a[4], b[4];
#pragma unroll
            for (int i = 0; i < 4; ++i) a[i] = As[ty * 4 + i][kk];
#pragma unroll
            for (int j = 0; j < 4; ++j) b[j] = Bs[kk][tx * 4 + j];
#pragma unroll
            for (int i = 0; i < 4; ++i)
#pragma unroll
                for (int j = 0; j < 4; ++j)
                    acc[i][j] = fmaf(a[i], b[j], acc[i][j]);
        }
        __syncthreads();
    }

#pragma unroll
    for (int i = 0; i < 4; ++i) {
        int row = row0 + ty * 4 + i;
#pragma unroll
        for (int j = 0; j < 4; ++j) {
            int jglob = j0 + tx * 4 + j;
            if (jglob < 256) {
                q_out[(size_t)row * EDIM + jglob] = (acc[i][j] + b_in[jglob]) * SCALING;
            } else if (jglob < 288) {
                int d = jglob - 256;
                khs_out[(size_t)row * HDIM + d] = acc[i][j] + bksum[d];
            }
        }
    }
}

// ---------------------------------------------------------------------------
// K3a: histogram of src
// ---------------------------------------------------------------------------
__global__ __launch_bounds__(256) void hist_kernel(const int* __restrict__ edge_index,
                                                   int* __restrict__ counts) {
    int e = blockIdx.x * 256 + threadIdx.x;
    atomicAdd(counts + edge_index[e], 1);
}

// ---------------------------------------------------------------------------
// K3b: exclusive prefix scan of counts[8192] -> offsets[8193], cursor copy
// ---------------------------------------------------------------------------
__global__ __launch_bounds__(256) void scan_kernel(const int* __restrict__ counts,
                                                   int* __restrict__ offsets,
                                                   int* __restrict__ cursor) {
    __shared__ int part[256];
    int t = threadIdx.x;
    int base = t * 32;
    int local[32];
    int s = 0;
#pragma unroll
    for (int i = 0; i < 32; ++i) { local[i] = counts[base + i]; s += local[i]; }
    part[t] = s;
    __syncthreads();
    for (int st = 1; st < 256; st <<= 1) {
        int v = (t >= st) ? part[t - st] : 0;
        __syncthreads();
        part[t] += v;
        __syncthreads();
    }
    int off = part[t] - s;   // exclusive
#pragma unroll
    for (int i = 0; i < 32; ++i) {
        offsets[base + i] = off;
        cursor[base + i]  = off;
        off += local[i];
    }
    if (t == 255) offsets[8192] = off;
}

// ---------------------------------------------------------------------------
// K3c: scatter edges into src-grouped order (dst and edge-id arrays).
// ---------------------------------------------------------------------------
__global__ __launch_bounds__(256) void scatter_kernel(const int* __restrict__ edge_index,
                                                      int* __restrict__ cursor,
                                                      int* __restrict__ sorted_dst,
                                                      int* __restrict__ sorted_eid) {
    int e = blockIdx.x * 256 + threadIdx.x;
    int src = edge_index[e];
    int dst = edge_index[NEDGE + e];
    int pos = atomicAdd(cursor + src, 1);
    sorted_dst[pos] = dst;
    sorted_eid[pos] = e;
}

// ---------------------------------------------------------------------------
// K3d: per-src segment reduction, NO atomics.
//   col[h,j] = (sum_{e:src=j} q[dst_e,h,:]) . khs[j,:] + sum_{e:src=j} bias[h,e]
// ---------------------------------------------------------------------------
__global__ __launch_bounds__(256) void src_edge_kernel(const float* __restrict__ q,
                                                       const float* __restrict__ khs,
                                                       const float* __restrict__ bias,
                                                       const int* __restrict__ sorted_dst,
                                                       const int* __restrict__ sorted_eid,
                                                       const int* __restrict__ offsets,
                                                       float* __restrict__ col) {
    int wslot = threadIdx.x >> 6;
    int lane  = threadIdx.x & 63;
    int j     = blockIdx.x * 4 + wslot;
    int start = offsets[j], end = offsets[j + 1];
    if (start == end) return;   // untouched node: col never read

    int sub = lane & 7, grp = lane >> 3;
    const float4* q4 = (const float4*)q;

    float4 a0 = make_float4(0.f, 0.f, 0.f, 0.f);
    float4 a1 = make_float4(0.f, 0.f, 0.f, 0.f);
    int p = start;
    for (; p + 1 < end; p += 2) {
        int d0 = sorted_dst[p];
        int d1 = sorted_dst[p + 1];
        float4 v0 = q4[(size_t)d0 * 64 + lane];
        float4 v1 = q4[(size_t)d1 * 64 + lane];
        a0.x += v0.x; a0.y += v0.y; a0.z += v0.z; a0.w += v0.w;
        a1.x += v1.x; a1.y += v1.y; a1.z += v1.z; a1.w += v1.w;
    }
    if (p < end) {
        int d0 = sorted_dst[p];
        float4 v0 = q4[(size_t)d0 * 64 + lane];
        a0.x += v0.x; a0.y += v0.y; a0.z += v0.z; a0.w += v0.w;
    }
    a0.x += a1.x; a0.y += a1.y; a0.z += a1.z; a0.w += a1.w;

    float ab = 0.f;
    for (int pb = start + grp; pb < end; pb += 8)
        ab += bias[(size_t)sub * NEDGE + sorted_eid[pb]];
    ab += __shfl_xor(ab, 8);
    ab += __shfl_xor(ab, 16);
    ab += __shfl_xor(ab, 32);

    const float4 kv = *(const float4*)(khs + (size_t)j * HDIM + sub * 4);
    float pd = a0.x * kv.x + a0.y * kv.y + a0.z * kv.z + a0.w * kv.w;
    pd += __shfl_xor(pd, 1);
    pd += __shfl_xor(pd, 2);
    pd += __shfl_xor(pd, 4);

    if (grp == sub)
        col[(size_t)grp * N_NODES + j] = pd + ab;
}

// ---------------------------------------------------------------------------
// K4a: per-head softmax over nodes; touched derived from offsets run length
// ---------------------------------------------------------------------------
__global__ __launch_bounds__(256) void softmax_kernel(const float* __restrict__ col,
                                                      const int* __restrict__ offsets,
                                                      float* __restrict__ attn) {
    int h = blockIdx.x;
    const float* c = col + (size_t)h * N_NODES;
    float* a = attn + (size_t)h * N_NODES;
    __shared__ float red[256];
    int t = threadIdx.x;

    float m = -INFINITY;
    for (int n = t; n < N_NODES; n += 256)
        if (offsets[n + 1] > offsets[n]) m = fmaxf(m, c[n]);
    red[t] = m; __syncthreads();
    for (int st = 128; st; st >>= 1) {
        if (t < st) red[t] = fmaxf(red[t], red[t + st]);
        __syncthreads();
    }
    m = red[0]; __syncthreads();

    float sum = 0.f;
    for (int n = t; n < N_NODES; n += 256) {
        float e = (offsets[n + 1] > offsets[n]) ? expf(c[n] - m) : 0.f;
        a[n] = e;
        sum += e;
    }
    red[t] = sum; __syncthreads();
    for (int st = 128; st; st >>= 1) {
        if (t < st) red[t] += red[t + st];
        __syncthreads();
    }
    float inv = 1.f / red[0];
    for (int n = t; n < N_NODES; n += 256)
        a[n] *= inv;
}

// ---------------------------------------------------------------------------
// K4b: partials: spart[b][h][c] = sum_{n in chunk b} attn[h,n] * query[n,c]
// 256 blocks x 32 rows; query row loaded ONCE, reused for all 8 heads.
// ---------------------------------------------------------------------------
__global__ __launch_bounds__(256) void sweight_kernel(const float* __restrict__ attn,
                                                      const float* __restrict__ query,
                                                      float* __restrict__ spart) {
    int b  = blockIdx.x;
    int n0 = b * SW_CHUNK;
    int t  = threadIdx.x;           // column c
    __shared__ float aw[HEADS][SW_CHUNK];

    // 8*32 = 256 loads: thread i -> head i>>5, n = i&31 (coalesced per 32)
    aw[t >> 5][t & 31] = attn[(size_t)(t >> 5) * N_NODES + n0 + (t & 31)];
    __syncthreads();

    float acc[HEADS];
#pragma unroll
    for (int h = 0; h < HEADS; ++h) acc[h] = 0.f;

#pragma unroll 4
    for (int n = 0; n < SW_CHUNK; ++n) {
        float qv = query[(size_t)(n0 + n) * EDIM + t];
#pragma unroll
        for (int h = 0; h < HEADS; ++h)
            acc[h] = fmaf(aw[h][n], qv, acc[h]);
    }
#pragma unroll
    for (int h = 0; h < HEADS; ++h)
        spart[((size_t)b * HEADS + h) * EDIM + t] = acc[h];
}

// ---------------------------------------------------------------------------
// K4c: s[h][c] = sum_b spart[b][h][c]
// ---------------------------------------------------------------------------
__global__ __launch_bounds__(256) void sreduce_kernel(const float* __restrict__ spart,
                                                      float* __restrict__ s) {
    int h = blockIdx.x, c = threadIdx.x;
    float acc = 0.f;
    for (int b = 0; b < SW_BLOCKS; ++b)
        acc += spart[((size_t)b * HEADS + h) * EDIM + c];
    s[(size_t)h * EDIM + c] = acc;
}

// ---------------------------------------------------------------------------
// K5a: of[j] = b_in[512+j] + s[j>>5,:] . W_in[512+j,:]   (256 blocks x 64)
// ---------------------------------------------------------------------------
__global__ __launch_bounds__(64) void gemv1_kernel(const float* __restrict__ s,
                                                   const float* __restrict__ W_in,
                                                   const float* __restrict__ b_in,
                                                   float* __restrict__ of) {
    int j = blockIdx.x, lane = threadIdx.x;
    const float4 w  = ((const float4*)(W_in + (size_t)(2 * EDIM + j) * EDIM))[lane];
    const float4 sv = ((const float4*)(s + (size_t)(j >> 5) * EDIM))[lane];
    float p = w.x * sv.x + w.y * sv.y + w.z * sv.z + w.w * sv.w;
    p += __shfl_xor(p, 1);  p += __shfl_xor(p, 2);  p += __shfl_xor(p, 4);
    p += __shfl_xor(p, 8);  p += __shfl_xor(p, 16); p += __shfl_xor(p, 32);
    if (lane == 0) of[j] = p + b_in[2 * EDIM + j];
}

// ---------------------------------------------------------------------------
// K5b: r[i] = b_out[i] + W_out[i,:] . of   (256 blocks x 64)
// ---------------------------------------------------------------------------
__global__ __launch_bounds__(64) void gemv2_kernel(const float* __restrict__ of,
                                                   const float* __restrict__ W_out,
                                                   const float* __restrict__ b_out,
                                                   float* __restrict__ r) {
    int i = blockIdx.x, lane = threadIdx.x;
    const float4 w = ((const float4*)(W_out + (size_t)i * EDIM))[lane];
    const float4 v = ((const float4*)of)[lane];
    float p = w.x * v.x + w.y * v.y + w.z * v.z + w.w * v.w;
    p += __shfl_xor(p, 1);  p += __shfl_xor(p, 2);  p += __shfl_xor(p, 4);
    p += __shfl_xor(p, 8);  p += __shfl_xor(p, 16); p += __shfl_xor(p, 32);
    if (lane == 0) r[i] = p + b_out[i];
}

// ---------------------------------------------------------------------------
// K6: broadcast row r to all N rows of out.
// ---------------------------------------------------------------------------
__global__ __launch_bounds__(256) void bcast_kernel(const float* __restrict__ r,
                                                    float* __restrict__ out) {
    int idx = blockIdx.x * blockDim.x + threadIdx.x;
    const float4* r4 = (const float4*)r;
    ((float4*)out)[idx] = r4[idx & 63];
}

// ---------------------------------------------------------------------------
extern "C" void kernel_launch(void* const* d_in, const int* in_sizes, int n_in,
                              void* d_out, int out_size, void* d_ws, size_t ws_size,
                              hipStream_t stream) {
    const float* query     = (const float*)d_in[0];
    const int*   edge_idx  = (const int*)d_in[1];
    const float* attn_bias = (const float*)d_in[2];
    const float* W_in      = (const float*)d_in[3];
    const float* b_in      = (const float*)d_in[4];
    const float* W_out     = (const float*)d_in[5];
    const float* b_out     = (const float*)d_in[6];
    float* out = (float*)d_out;
    float* ws  = (float*)d_ws;

    float* q          = ws;                            // 2,097,152
    float* khs        = q + 2097152;                   //   262,144
    float* Wksum      = khs + 262144;                  //     8,192
    float* bksum      = Wksum + 8192;                  //        64
    float* r          = bksum + 64;                    //       256
    float* of         = r + 256;                       //       256
    float* s          = of + 256;                      //     2,048
    float* spart      = s + 2048;                      //   524,288
    int*   counts     = (int*)(spart + 524288);        //     8,192 (zeroed)
    int*   cursor     = counts + 8192;                 //     8,192
    int*   offsets    = cursor + 8192;                 //     8,200
    int*   sorted_dst = offsets + 8200;                //   262,144
    int*   sorted_eid = sorted_dst + 262144;           //   262,144
    float* col        = (float*)(sorted_eid + 262144); //    65,536
    float* attn       = col + 65536;                   //    65,536

    hipMemsetAsync(counts, 0, (size_t)8192 * 4, stream);

    wksum_kernel<<<32, 256, 0, stream>>>(W_in, b_in, Wksum, bksum);

    dim3 g1(N_NODES / 64, 5);
    qk_gemm<<<g1, 256, 0, stream>>>(query, W_in, b_in, Wksum, bksum, q, khs);

    hist_kernel<<<NEDGE / 256, 256, 0, stream>>>(edge_idx, counts);
    scan_kernel<<<1, 256, 0, stream>>>(counts, offsets, cursor);
    scatter_kernel<<<NEDGE / 256, 256, 0, stream>>>(edge_idx, cursor,
                                                    sorted_dst, sorted_eid);
    src_edge_kernel<<<N_NODES / 4, 256, 0, stream>>>(q, khs, attn_bias,
                                                     sorted_dst, sorted_eid,
                                                     offsets, col);

    softmax_kernel<<<HEADS, 256, 0, stream>>>(col, offsets, attn);

    sweight_kernel<<<SW_BLOCKS, 256, 0, stream>>>(attn, query, spart);
    sreduce_kernel<<<HEADS, 256, 0, stream>>>(spart, s);

    gemv1_kernel<<<EDIM, 64, 0, stream>>>(s, W_in, b_in, of);
    gemv2_kernel<<<EDIM, 64, 0, stream>>>(of, W_out, b_out, r);

    bcast_kernel<<<(N_NODES * EDIM / 4) / 256, 256, 0, stream>>>(r, out);
}

// Round 5
// 175.396 us; speedup vs baseline: 2.5046x; 1.1796x over previous
//
#include <hip/hip_runtime.h>
#include <hip/hip_bf16.h>
#include <math.h>

#define N_NODES 8192
#define EDIM    256
#define HEADS   8
#define HDIM    32
#define NEDGE   262144
#define SCALING 0.17677669529663687f   // 1/sqrt(32)
#define SW_CHUNK 32
#define SW_BLOCKS (N_NODES / SW_CHUNK)   // 256

__device__ __forceinline__ float bf2f(unsigned short u) {
    return __uint_as_float(((unsigned)u) << 16);
}
__device__ __forceinline__ unsigned short f2bf(float f) {
    __hip_bfloat16 h = __float2bfloat16(f);
    return *reinterpret_cast<unsigned short*>(&h);
}
__device__ __forceinline__ float4 cvt4(ushort4 u) {
    return make_float4(bf2f(u.x), bf2f(u.y), bf2f(u.z), bf2f(u.w));
}

// ---------------------------------------------------------------------------
// K2: Wksum[d,c] = sum_h W_in[256 + h*32 + d, c];  bksum[d] = sum_h b_in[...]
// ---------------------------------------------------------------------------
__global__ void wksum_kernel(const float* __restrict__ W_in,
                             const float* __restrict__ b_in,
                             float* __restrict__ Wksum,
                             float* __restrict__ bksum) {
    int idx = blockIdx.x * 256 + threadIdx.x;   // 8192 = 32*256
    int d = idx >> 8, c = idx & 255;
    float sum = 0.f;
    for (int h = 0; h < HEADS; ++h)
        sum += W_in[(size_t)(EDIM + h * HDIM + d) * EDIM + c];
    Wksum[idx] = sum;
    if (c == 0) {
        float bs = 0.f;
        for (int h = 0; h < HEADS; ++h)
            bs += b_in[EDIM + h * HDIM + d];
        bksum[d] = bs;
    }
}

// ---------------------------------------------------------------------------
// K1: tiled f32 GEMM: out[n, j] = query[n,:] . Wsel[j,:]  (j in [0,288))
//   j < 256  -> q_bf (bf16, scaled);  j >= 256 -> khs (f32)
// ---------------------------------------------------------------------------
__global__ __launch_bounds__(256) void qk_gemm(const float* __restrict__ query,
                                               const float* __restrict__ W_in,
                                               const float* __restrict__ b_in,
                                               const float* __restrict__ Wksum,
                                               const float* __restrict__ bksum,
                                               unsigned short* __restrict__ q_bf,
                                               float* __restrict__ khs_out) {
    __shared__ float As[64][17];
    __shared__ float Bs[16][65];

    int row0 = blockIdx.x * 64;
    int j0   = blockIdx.y * 64;
    int t    = threadIdx.x;
    int tx = t & 15, ty = t >> 4;

    float acc[4][4];
#pragma unroll
    for (int i = 0; i < 4; ++i)
#pragma unroll
        for (int j = 0; j < 4; ++j) acc[i][j] = 0.f;

    int lm  = t >> 2;          // 0..63 row (A) / j (B)
    int lk4 = (t & 3) * 4;     // 0,4,8,12

    for (int k0 = 0; k0 < EDIM; k0 += 16) {
        {
            const float4 a = *(const float4*)(query + (size_t)(row0 + lm) * EDIM + k0 + lk4);
            As[lm][lk4 + 0] = a.x; As[lm][lk4 + 1] = a.y;
            As[lm][lk4 + 2] = a.z; As[lm][lk4 + 3] = a.w;
        }
        {
            int jglob = j0 + lm;
            float4 b = make_float4(0.f, 0.f, 0.f, 0.f);
            if (jglob < 288) {
                const float* wrow = (jglob < 256)
                    ? (W_in + (size_t)jglob * EDIM)
                    : (Wksum + (size_t)(jglob - 256) * EDIM);
                b = *(const float4*)(wrow + k0 + lk4);
            }
            Bs[lk4 + 0][lm] = b.x; Bs[lk4 + 1][lm] = b.y;
            Bs[lk4 + 2][lm] = b.z; Bs[lk4 + 3][lm] = b.w;
        }
        __syncthreads();
#pragma unroll
        for (int kk = 0; kk < 16; ++kk) {
            float a[4], b[4];
#pragma unroll
            for (int i = 0; i < 4; ++i) a[i] = As[ty * 4 + i][kk];
#pragma unroll
            for (int j = 0; j < 4; ++j) b[j] = Bs[kk][tx * 4 + j];
#pragma unroll
            for (int i = 0; i < 4; ++i)
#pragma unroll
                for (int j = 0; j < 4; ++j)
                    acc[i][j] = fmaf(a[i], b[j], acc[i][j]);
        }
        __syncthreads();
    }

#pragma unroll
    for (int i = 0; i < 4; ++i) {
        int row = row0 + ty * 4 + i;
#pragma unroll
        for (int j = 0; j < 4; ++j) {
            int jglob = j0 + tx * 4 + j;
            if (jglob < 256) {
                q_bf[(size_t)row * EDIM + jglob] =
                    f2bf((acc[i][j] + b_in[jglob]) * SCALING);
            } else if (jglob < 288) {
                int d = jglob - 256;
                khs_out[(size_t)row * HDIM + d] = acc[i][j] + bksum[d];
            }
        }
    }
}

// ---------------------------------------------------------------------------
// K3a: histogram of src
// ---------------------------------------------------------------------------
__global__ __launch_bounds__(256) void hist_kernel(const int* __restrict__ edge_index,
                                                   int* __restrict__ counts) {
    int e = blockIdx.x * 256 + threadIdx.x;
    atomicAdd(counts + edge_index[e], 1);
}

// ---------------------------------------------------------------------------
// K3b: exclusive prefix scan of counts[8192] -> offsets[8193], cursor copy
// ---------------------------------------------------------------------------
__global__ __launch_bounds__(256) void scan_kernel(const int* __restrict__ counts,
                                                   int* __restrict__ offsets,
                                                   int* __restrict__ cursor) {
    __shared__ int part[256];
    int t = threadIdx.x;
    int base = t * 32;
    int local[32];
    int s = 0;
#pragma unroll
    for (int i = 0; i < 32; ++i) { local[i] = counts[base + i]; s += local[i]; }
    part[t] = s;
    __syncthreads();
    for (int st = 1; st < 256; st <<= 1) {
        int v = (t >= st) ? part[t - st] : 0;
        __syncthreads();
        part[t] += v;
        __syncthreads();
    }
    int off = part[t] - s;   // exclusive
#pragma unroll
    for (int i = 0; i < 32; ++i) {
        offsets[base + i] = off;
        cursor[base + i]  = off;
        off += local[i];
    }
    if (t == 255) offsets[8192] = off;
}

// ---------------------------------------------------------------------------
// K3c: scatter edges into src-grouped order.  Writes sorted_dst and a packed
// bf16x8 per-edge bias record (coalesced bias reads here; sequential reads in
// src_edge_kernel — kills the random line-granularity bias gather).
// ---------------------------------------------------------------------------
__global__ __launch_bounds__(256) void scatter_kernel(const int* __restrict__ edge_index,
                                                      const float* __restrict__ bias,
                                                      int* __restrict__ cursor,
                                                      int* __restrict__ sorted_dst,
                                                      uint4* __restrict__ sorted_bias) {
    int e = blockIdx.x * 256 + threadIdx.x;
    int src = edge_index[e];
    int dst = edge_index[NEDGE + e];
    int pos = atomicAdd(cursor + src, 1);
    sorted_dst[pos] = dst;
    unsigned b0 = f2bf(bias[0 * NEDGE + e]) | ((unsigned)f2bf(bias[1 * NEDGE + e]) << 16);
    unsigned b1 = f2bf(bias[2 * NEDGE + e]) | ((unsigned)f2bf(bias[3 * NEDGE + e]) << 16);
    unsigned b2 = f2bf(bias[4 * NEDGE + e]) | ((unsigned)f2bf(bias[5 * NEDGE + e]) << 16);
    unsigned b3 = f2bf(bias[6 * NEDGE + e]) | ((unsigned)f2bf(bias[7 * NEDGE + e]) << 16);
    sorted_bias[pos] = make_uint4(b0, b1, b2, b3);
}

// ---------------------------------------------------------------------------
// K3d: per-src segment reduction, NO atomics.
//   col[h,j] = (sum_{e:src=j} q[dst_e,h,:]) . khs[j,:] + sum_{e:src=j} bias[h,e]
// q is bf16 (8B/lane/edge); 4-deep unroll for memory-level parallelism.
// ---------------------------------------------------------------------------
__global__ __launch_bounds__(256) void src_edge_kernel(const unsigned short* __restrict__ q_bf,
                                                       const float* __restrict__ khs,
                                                       const int* __restrict__ sorted_dst,
                                                       const unsigned short* __restrict__ sorted_bias,
                                                       const int* __restrict__ offsets,
                                                       float* __restrict__ col) {
    int wslot = threadIdx.x >> 6;
    int lane  = threadIdx.x & 63;
    int j     = blockIdx.x * 4 + wslot;
    int start = offsets[j], end = offsets[j + 1];
    if (start == end) return;   // untouched node: col never read

    int sub = lane & 7, grp = lane >> 3;
    const ushort4* q4 = (const ushort4*)q_bf;   // row = 64 ushort4

    float4 a0 = make_float4(0.f, 0.f, 0.f, 0.f);
    float4 a1 = make_float4(0.f, 0.f, 0.f, 0.f);
    float4 a2 = make_float4(0.f, 0.f, 0.f, 0.f);
    float4 a3 = make_float4(0.f, 0.f, 0.f, 0.f);
    int p = start;
    for (; p + 3 < end; p += 4) {
        ushort4 u0 = q4[(size_t)sorted_dst[p + 0] * 64 + lane];
        ushort4 u1 = q4[(size_t)sorted_dst[p + 1] * 64 + lane];
        ushort4 u2 = q4[(size_t)sorted_dst[p + 2] * 64 + lane];
        ushort4 u3 = q4[(size_t)sorted_dst[p + 3] * 64 + lane];
        float4 v0 = cvt4(u0), v1 = cvt4(u1), v2 = cvt4(u2), v3 = cvt4(u3);
        a0.x += v0.x; a0.y += v0.y; a0.z += v0.z; a0.w += v0.w;
        a1.x += v1.x; a1.y += v1.y; a1.z += v1.z; a1.w += v1.w;
        a2.x += v2.x; a2.y += v2.y; a2.z += v2.z; a2.w += v2.w;
        a3.x += v3.x; a3.y += v3.y; a3.z += v3.z; a3.w += v3.w;
    }
    for (; p < end; ++p) {
        float4 v0 = cvt4(q4[(size_t)sorted_dst[p] * 64 + lane]);
        a0.x += v0.x; a0.y += v0.y; a0.z += v0.z; a0.w += v0.w;
    }
    a0.x += a1.x + a2.x + a3.x;
    a0.y += a1.y + a2.y + a3.y;
    a0.z += a1.z + a2.z + a3.z;
    a0.w += a1.w + a2.w + a3.w;

    // bias: 8-lane group grp handles positions start+grp, +8...; lane sub = head
    float ab = 0.f;
    for (int pb = start + grp; pb < end; pb += 8)
        ab += bf2f(sorted_bias[(size_t)pb * 8 + sub]);
    ab += __shfl_xor(ab, 8);
    ab += __shfl_xor(ab, 16);
    ab += __shfl_xor(ab, 32);          // every lane: bias sum for head=sub

    const float4 kv = *(const float4*)(khs + (size_t)j * HDIM + sub * 4);
    float pd = a0.x * kv.x + a0.y * kv.y + a0.z * kv.z + a0.w * kv.w;
    pd += __shfl_xor(pd, 1);
    pd += __shfl_xor(pd, 2);
    pd += __shfl_xor(pd, 4);           // every lane of 8-group: dot for head=grp

    if (grp == sub)
        col[(size_t)grp * N_NODES + j] = pd + ab;
}

// ---------------------------------------------------------------------------
// K4a: per-head softmax over nodes; touched derived from offsets run length
// ---------------------------------------------------------------------------
__global__ __launch_bounds__(256) void softmax_kernel(const float* __restrict__ col,
                                                      const int* __restrict__ offsets,
                                                      float* __restrict__ attn) {
    int h = blockIdx.x;
    const float* c = col + (size_t)h * N_NODES;
    float* a = attn + (size_t)h * N_NODES;
    __shared__ float red[256];
    int t = threadIdx.x;

    float m = -INFINITY;
    for (int n = t; n < N_NODES; n += 256)
        if (offsets[n + 1] > offsets[n]) m = fmaxf(m, c[n]);
    red[t] = m; __syncthreads();
    for (int st = 128; st; st >>= 1) {
        if (t < st) red[t] = fmaxf(red[t], red[t + st]);
        __syncthreads();
    }
    m = red[0]; __syncthreads();

    float sum = 0.f;
    for (int n = t; n < N_NODES; n += 256) {
        float e = (offsets[n + 1] > offsets[n]) ? expf(c[n] - m) : 0.f;
        a[n] = e;
        sum += e;
    }
    red[t] = sum; __syncthreads();
    for (int st = 128; st; st >>= 1) {
        if (t < st) red[t] += red[t + st];
        __syncthreads();
    }
    float inv = 1.f / red[0];
    for (int n = t; n < N_NODES; n += 256)
        a[n] *= inv;
}

// ---------------------------------------------------------------------------
// K4b: partials: spart[b][h][c] = sum_{n in chunk b} attn[h,n] * query[n,c]
// ---------------------------------------------------------------------------
__global__ __launch_bounds__(256) void sweight_kernel(const float* __restrict__ attn,
                                                      const float* __restrict__ query,
                                                      float* __restrict__ spart) {
    int b  = blockIdx.x;
    int n0 = b * SW_CHUNK;
    int t  = threadIdx.x;           // column c
    __shared__ float aw[HEADS][SW_CHUNK];

    aw[t >> 5][t & 31] = attn[(size_t)(t >> 5) * N_NODES + n0 + (t & 31)];
    __syncthreads();

    float acc[HEADS];
#pragma unroll
    for (int h = 0; h < HEADS; ++h) acc[h] = 0.f;

#pragma unroll 4
    for (int n = 0; n < SW_CHUNK; ++n) {
        float qv = query[(size_t)(n0 + n) * EDIM + t];
#pragma unroll
        for (int h = 0; h < HEADS; ++h)
            acc[h] = fmaf(aw[h][n], qv, acc[h]);
    }
#pragma unroll
    for (int h = 0; h < HEADS; ++h)
        spart[((size_t)b * HEADS + h) * EDIM + t] = acc[h];
}

// ---------------------------------------------------------------------------
// K4c: s[h][c] = sum_b spart[b][h][c]
// ---------------------------------------------------------------------------
__global__ __launch_bounds__(256) void sreduce_kernel(const float* __restrict__ spart,
                                                      float* __restrict__ s) {
    int h = blockIdx.x, c = threadIdx.x;
    float acc = 0.f;
    for (int b = 0; b < SW_BLOCKS; ++b)
        acc += spart[((size_t)b * HEADS + h) * EDIM + c];
    s[(size_t)h * EDIM + c] = acc;
}

// ---------------------------------------------------------------------------
// K5a: of[j] = b_in[512+j] + s[j>>5,:] . W_in[512+j,:]
// ---------------------------------------------------------------------------
__global__ __launch_bounds__(64) void gemv1_kernel(const float* __restrict__ s,
                                                   const float* __restrict__ W_in,
                                                   const float* __restrict__ b_in,
                                                   float* __restrict__ of) {
    int j = blockIdx.x, lane = threadIdx.x;
    const float4 w  = ((const float4*)(W_in + (size_t)(2 * EDIM + j) * EDIM))[lane];
    const float4 sv = ((const float4*)(s + (size_t)(j >> 5) * EDIM))[lane];
    float p = w.x * sv.x + w.y * sv.y + w.z * sv.z + w.w * sv.w;
    p += __shfl_xor(p, 1);  p += __shfl_xor(p, 2);  p += __shfl_xor(p, 4);
    p += __shfl_xor(p, 8);  p += __shfl_xor(p, 16); p += __shfl_xor(p, 32);
    if (lane == 0) of[j] = p + b_in[2 * EDIM + j];
}

// ---------------------------------------------------------------------------
// K5b: r[i] = b_out[i] + W_out[i,:] . of
// ---------------------------------------------------------------------------
__global__ __launch_bounds__(64) void gemv2_kernel(const float* __restrict__ of,
                                                   const float* __restrict__ W_out,
                                                   const float* __restrict__ b_out,
                                                   float* __restrict__ r) {
    int i = blockIdx.x, lane = threadIdx.x;
    const float4 w = ((const float4*)(W_out + (size_t)i * EDIM))[lane];
    const float4 v = ((const float4*)of)[lane];
    float p = w.x * v.x + w.y * v.y + w.z * v.z + w.w * v.w;
    p += __shfl_xor(p, 1);  p += __shfl_xor(p, 2);  p += __shfl_xor(p, 4);
    p += __shfl_xor(p, 8);  p += __shfl_xor(p, 16); p += __shfl_xor(p, 32);
    if (lane == 0) r[i] = p + b_out[i];
}

// ---------------------------------------------------------------------------
// K6: broadcast row r to all N rows of out.
// ---------------------------------------------------------------------------
__global__ __launch_bounds__(256) void bcast_kernel(const float* __restrict__ r,
                                                    float* __restrict__ out) {
    int idx = blockIdx.x * blockDim.x + threadIdx.x;
    const float4* r4 = (const float4*)r;
    ((float4*)out)[idx] = r4[idx & 63];
}

// ---------------------------------------------------------------------------
extern "C" void kernel_launch(void* const* d_in, const int* in_sizes, int n_in,
                              void* d_out, int out_size, void* d_ws, size_t ws_size,
                              hipStream_t stream) {
    const float* query     = (const float*)d_in[0];
    const int*   edge_idx  = (const int*)d_in[1];
    const float* attn_bias = (const float*)d_in[2];
    const float* W_in      = (const float*)d_in[3];
    const float* b_in      = (const float*)d_in[4];
    const float* W_out     = (const float*)d_in[5];
    const float* b_out     = (const float*)d_in[6];
    float* out = (float*)d_out;
    float* ws  = (float*)d_ws;

    unsigned short* q_bf   = (unsigned short*)ws;        // 2,097,152 ushort (=1,048,576 f)
    float* khs        = ws + 1048576;                    //   262,144
    float* Wksum      = khs + 262144;                    //     8,192
    float* bksum      = Wksum + 8192;                    //        64
    float* r          = bksum + 64;                      //       256
    float* of         = r + 256;                         //       256
    float* s          = of + 256;                        //     2,048
    float* spart      = s + 2048;                        //   524,288
    int*   counts     = (int*)(spart + 524288);          //     8,192 (zeroed)
    int*   cursor     = counts + 8192;                   //     8,192
    int*   offsets    = cursor + 8192;                   //     8,200
    int*   sorted_dst = offsets + 8200;                  //   262,144
    uint4* sorted_bias = (uint4*)(sorted_dst + 262144);  //   262,144 uint4 (=1,048,576 f)
    float* col        = (float*)(sorted_bias + 262144);  //    65,536
    float* attn       = col + 65536;                     //    65,536

    hipMemsetAsync(counts, 0, (size_t)8192 * 4, stream);

    wksum_kernel<<<32, 256, 0, stream>>>(W_in, b_in, Wksum, bksum);

    dim3 g1(N_NODES / 64, 5);
    qk_gemm<<<g1, 256, 0, stream>>>(query, W_in, b_in, Wksum, bksum, q_bf, khs);

    hist_kernel<<<NEDGE / 256, 256, 0, stream>>>(edge_idx, counts);
    scan_kernel<<<1, 256, 0, stream>>>(counts, offsets, cursor);
    scatter_kernel<<<NEDGE / 256, 256, 0, stream>>>(edge_idx, attn_bias, cursor,
                                                    sorted_dst, sorted_bias);
    src_edge_kernel<<<N_NODES / 4, 256, 0, stream>>>(q_bf, khs, sorted_dst,
                                                     (const unsigned short*)sorted_bias,
                                                     offsets, col);

    softmax_kernel<<<HEADS, 256, 0, stream>>>(col, offsets, attn);

    sweight_kernel<<<SW_BLOCKS, 256, 0, stream>>>(attn, query, spart);
    sreduce_kernel<<<HEADS, 256, 0, stream>>>(spart, s);

    gemv1_kernel<<<EDIM, 64, 0, stream>>>(s, W_in, b_in, of);
    gemv2_kernel<<<EDIM, 64, 0, stream>>>(of, W_out, b_out, r);

    bcast_kernel<<<(N_NODES * EDIM / 4) / 256, 256, 0, stream>>>(r, out);
}

// Round 6
// 160.501 us; speedup vs baseline: 2.7370x; 1.0928x over previous
//
#include <hip/hip_runtime.h>
#include <hip/hip_bf16.h>
#include <math.h>

#define N_NODES 8192
#define EDIM    256
#define HEADS   8
#define HDIM    32
#define NEDGE   262144
#define SCALING 0.17677669529663687f   // 1/sqrt(32)
#define SW_CHUNK 32
#define SW_BLOCKS (N_NODES / SW_CHUNK)   // 256

typedef __attribute__((ext_vector_type(8))) short bf16x8;
typedef __attribute__((ext_vector_type(4))) float f32x4;

__device__ __forceinline__ float bf2f(unsigned short u) {
    return __uint_as_float(((unsigned)u) << 16);
}
__device__ __forceinline__ unsigned short f2bf(float f) {
    __hip_bfloat16 h = __float2bfloat16(f);
    return *reinterpret_cast<unsigned short*>(&h);
}
__device__ __forceinline__ float4 cvt4(ushort4 u) {
    return make_float4(bf2f(u.x), bf2f(u.y), bf2f(u.z), bf2f(u.w));
}

// ---------------------------------------------------------------------------
// K0a: zero counts (replaces hipMemsetAsync / rocclr fill)
// ---------------------------------------------------------------------------
__global__ __launch_bounds__(256) void zero_kernel(int* __restrict__ counts) {
    counts[blockIdx.x * 256 + threadIdx.x] = 0;
}

// ---------------------------------------------------------------------------
// K0b: convert query f32 -> bf16 (row-major [N][E])
// ---------------------------------------------------------------------------
__global__ __launch_bounds__(256) void convq_kernel(const float* __restrict__ query,
                                                    unsigned short* __restrict__ qbf) {
    int idx = blockIdx.x * 256 + threadIdx.x;      // over N*E/4
    float4 v = ((const float4*)query)[idx];
    ushort4 u = make_ushort4(f2bf(v.x), f2bf(v.y), f2bf(v.z), f2bf(v.w));
    ((ushort4*)qbf)[idx] = u;
}

// ---------------------------------------------------------------------------
// K0c: Wall_bf[288][256]: rows 0..255 = bf16(W_in[j]); rows 256..287 =
//      bf16(sum_h W_in[256+h*32+d]);  bksum[d] = sum_h b_in[256+h*32+d]
// ---------------------------------------------------------------------------
__global__ __launch_bounds__(256) void prepw_kernel(const float* __restrict__ W_in,
                                                    const float* __restrict__ b_in,
                                                    unsigned short* __restrict__ Wall,
                                                    float* __restrict__ bksum) {
    int row = blockIdx.x;        // 0..287
    int c   = threadIdx.x;
    if (row < 256) {
        Wall[(size_t)row * EDIM + c] = f2bf(W_in[(size_t)row * EDIM + c]);
    } else {
        int d = row - 256;
        float s = 0.f;
        for (int h = 0; h < HEADS; ++h)
            s += W_in[(size_t)(EDIM + h * HDIM + d) * EDIM + c];
        Wall[(size_t)row * EDIM + c] = f2bf(s);
        if (c == 0) {
            float bs = 0.f;
            for (int h = 0; h < HEADS; ++h)
                bs += b_in[EDIM + h * HDIM + d];
            bksum[d] = bs;
        }
    }
}

// ---------------------------------------------------------------------------
// K1: MFMA bf16 GEMM: out[n, j] = qbf[n,:] . Wall[j,:]  (j in [0,288))
//   j < 256 -> q_bf (bf16, scaled, +b_in);  j >= 256 -> khs f32 (+bksum)
// One wave per 16x16 output tile; K=256 in 8 x mfma_f32_16x16x32_bf16.
// A: lane holds row (l&15), k0=(l>>4)*8 (8 contiguous bf16).  B same with
// col=(l&15) from Wall row-major (= B^T).  D: row=(l>>4)*4+i, col=l&15.
// ---------------------------------------------------------------------------
__global__ __launch_bounds__(256) void qk_mfma(const unsigned short* __restrict__ qbf,
                                               const unsigned short* __restrict__ Wall,
                                               const float* __restrict__ b_in,
                                               const float* __restrict__ bksum,
                                               unsigned short* __restrict__ q_out,
                                               float* __restrict__ khs_out) {
    int wave = (blockIdx.x * 256 + (int)threadIdx.x) >> 6;   // 0..9215
    int lane = threadIdx.x & 63;
    int tr = wave & 511, tc = wave >> 9;                     // 512 x 18 tiles
    int row0 = tr * 16, col0 = tc * 16;
    int r = lane & 15;
    int kchunk = (lane >> 4);                                // 0..3 (8 bf16 each)

    const bf16x8* arow = (const bf16x8*)(qbf  + (size_t)(row0 + r) * EDIM);
    const bf16x8* brow = (const bf16x8*)(Wall + (size_t)(col0 + r) * EDIM);

    f32x4 acc = {0.f, 0.f, 0.f, 0.f};
#pragma unroll
    for (int ks = 0; ks < 8; ++ks) {
        bf16x8 a = arow[ks * 4 + kchunk];
        bf16x8 b = brow[ks * 4 + kchunk];
        acc = __builtin_amdgcn_mfma_f32_16x16x32_bf16(a, b, acc, 0, 0, 0);
    }

    int feat = col0 + r;
#pragma unroll
    for (int i = 0; i < 4; ++i) {
        int node = row0 + (lane >> 4) * 4 + i;
        if (feat < 256) {
            q_out[(size_t)node * EDIM + feat] = f2bf((acc[i] + b_in[feat]) * SCALING);
        } else {
            khs_out[(size_t)node * HDIM + (feat - 256)] = acc[i] + bksum[feat - 256];
        }
    }
}

// ---------------------------------------------------------------------------
// K3a: histogram of src
// ---------------------------------------------------------------------------
__global__ __launch_bounds__(256) void hist_kernel(const int* __restrict__ edge_index,
                                                   int* __restrict__ counts) {
    int e = blockIdx.x * 256 + threadIdx.x;
    atomicAdd(counts + edge_index[e], 1);
}

// ---------------------------------------------------------------------------
// K3b: exclusive prefix scan of counts[8192] -> offsets[8193], cursor copy
// ---------------------------------------------------------------------------
__global__ __launch_bounds__(256) void scan_kernel(const int* __restrict__ counts,
                                                   int* __restrict__ offsets,
                                                   int* __restrict__ cursor) {
    __shared__ int part[256];
    int t = threadIdx.x;
    int base = t * 32;
    int local[32];
    int s = 0;
#pragma unroll
    for (int i = 0; i < 32; ++i) { local[i] = counts[base + i]; s += local[i]; }
    part[t] = s;
    __syncthreads();
    for (int st = 1; st < 256; st <<= 1) {
        int v = (t >= st) ? part[t - st] : 0;
        __syncthreads();
        part[t] += v;
        __syncthreads();
    }
    int off = part[t] - s;   // exclusive
#pragma unroll
    for (int i = 0; i < 32; ++i) {
        offsets[base + i] = off;
        cursor[base + i]  = off;
        off += local[i];
    }
    if (t == 255) offsets[8192] = off;
}

// ---------------------------------------------------------------------------
// K3c: scatter edges into src-grouped order; packed bf16x8 bias records.
// ---------------------------------------------------------------------------
__global__ __launch_bounds__(256) void scatter_kernel(const int* __restrict__ edge_index,
                                                      const float* __restrict__ bias,
                                                      int* __restrict__ cursor,
                                                      int* __restrict__ sorted_dst,
                                                      uint4* __restrict__ sorted_bias) {
    int e = blockIdx.x * 256 + threadIdx.x;
    int src = edge_index[e];
    int dst = edge_index[NEDGE + e];
    int pos = atomicAdd(cursor + src, 1);
    sorted_dst[pos] = dst;
    unsigned b0 = f2bf(bias[0 * NEDGE + e]) | ((unsigned)f2bf(bias[1 * NEDGE + e]) << 16);
    unsigned b1 = f2bf(bias[2 * NEDGE + e]) | ((unsigned)f2bf(bias[3 * NEDGE + e]) << 16);
    unsigned b2 = f2bf(bias[4 * NEDGE + e]) | ((unsigned)f2bf(bias[5 * NEDGE + e]) << 16);
    unsigned b3 = f2bf(bias[6 * NEDGE + e]) | ((unsigned)f2bf(bias[7 * NEDGE + e]) << 16);
    sorted_bias[pos] = make_uint4(b0, b1, b2, b3);
}

// ---------------------------------------------------------------------------
// K3d: per-src segment reduction, NO atomics.
// ---------------------------------------------------------------------------
__global__ __launch_bounds__(256) void src_edge_kernel(const unsigned short* __restrict__ q_bf,
                                                       const float* __restrict__ khs,
                                                       const int* __restrict__ sorted_dst,
                                                       const unsigned short* __restrict__ sorted_bias,
                                                       const int* __restrict__ offsets,
                                                       float* __restrict__ col) {
    int wslot = threadIdx.x >> 6;
    int lane  = threadIdx.x & 63;
    int j     = blockIdx.x * 4 + wslot;
    int start = offsets[j], end = offsets[j + 1];
    if (start == end) return;   // untouched node: col never read

    int sub = lane & 7, grp = lane >> 3;
    const ushort4* q4 = (const ushort4*)q_bf;   // row = 64 ushort4

    float4 a0 = make_float4(0.f, 0.f, 0.f, 0.f);
    float4 a1 = make_float4(0.f, 0.f, 0.f, 0.f);
    float4 a2 = make_float4(0.f, 0.f, 0.f, 0.f);
    float4 a3 = make_float4(0.f, 0.f, 0.f, 0.f);
    int p = start;
    for (; p + 3 < end; p += 4) {
        ushort4 u0 = q4[(size_t)sorted_dst[p + 0] * 64 + lane];
        ushort4 u1 = q4[(size_t)sorted_dst[p + 1] * 64 + lane];
        ushort4 u2 = q4[(size_t)sorted_dst[p + 2] * 64 + lane];
        ushort4 u3 = q4[(size_t)sorted_dst[p + 3] * 64 + lane];
        float4 v0 = cvt4(u0), v1 = cvt4(u1), v2 = cvt4(u2), v3 = cvt4(u3);
        a0.x += v0.x; a0.y += v0.y; a0.z += v0.z; a0.w += v0.w;
        a1.x += v1.x; a1.y += v1.y; a1.z += v1.z; a1.w += v1.w;
        a2.x += v2.x; a2.y += v2.y; a2.z += v2.z; a2.w += v2.w;
        a3.x += v3.x; a3.y += v3.y; a3.z += v3.z; a3.w += v3.w;
    }
    for (; p < end; ++p) {
        float4 v0 = cvt4(q4[(size_t)sorted_dst[p] * 64 + lane]);
        a0.x += v0.x; a0.y += v0.y; a0.z += v0.z; a0.w += v0.w;
    }
    a0.x += a1.x + a2.x + a3.x;
    a0.y += a1.y + a2.y + a3.y;
    a0.z += a1.z + a2.z + a3.z;
    a0.w += a1.w + a2.w + a3.w;

    float ab = 0.f;
    for (int pb = start + grp; pb < end; pb += 8)
        ab += bf2f(sorted_bias[(size_t)pb * 8 + sub]);
    ab += __shfl_xor(ab, 8);
    ab += __shfl_xor(ab, 16);
    ab += __shfl_xor(ab, 32);          // every lane: bias sum for head=sub

    const float4 kv = *(const float4*)(khs + (size_t)j * HDIM + sub * 4);
    float pd = a0.x * kv.x + a0.y * kv.y + a0.z * kv.z + a0.w * kv.w;
    pd += __shfl_xor(pd, 1);
    pd += __shfl_xor(pd, 2);
    pd += __shfl_xor(pd, 4);           // every lane of 8-group: dot for head=grp

    if (grp == sub)
        col[(size_t)grp * N_NODES + j] = pd + ab;
}

// ---------------------------------------------------------------------------
// K4a: per-head softmax over nodes; touched derived from offsets run length
// ---------------------------------------------------------------------------
__global__ __launch_bounds__(256) void softmax_kernel(const float* __restrict__ col,
                                                      const int* __restrict__ offsets,
                                                      float* __restrict__ attn) {
    int h = blockIdx.x;
    const float* c = col + (size_t)h * N_NODES;
    float* a = attn + (size_t)h * N_NODES;
    __shared__ float red[256];
    int t = threadIdx.x;

    float m = -INFINITY;
    for (int n = t; n < N_NODES; n += 256)
        if (offsets[n + 1] > offsets[n]) m = fmaxf(m, c[n]);
    red[t] = m; __syncthreads();
    for (int st = 128; st; st >>= 1) {
        if (t < st) red[t] = fmaxf(red[t], red[t + st]);
        __syncthreads();
    }
    m = red[0]; __syncthreads();

    float sum = 0.f;
    for (int n = t; n < N_NODES; n += 256) {
        float e = (offsets[n + 1] > offsets[n]) ? expf(c[n] - m) : 0.f;
        a[n] = e;
        sum += e;
    }
    red[t] = sum; __syncthreads();
    for (int st = 128; st; st >>= 1) {
        if (t < st) red[t] += red[t + st];
        __syncthreads();
    }
    float inv = 1.f / red[0];
    for (int n = t; n < N_NODES; n += 256)
        a[n] *= inv;
}

// ---------------------------------------------------------------------------
// K4b: partials: spart[b][h][c] = sum_{n in chunk b} attn[h,n] * query[n,c]
// ---------------------------------------------------------------------------
__global__ __launch_bounds__(256) void sweight_kernel(const float* __restrict__ attn,
                                                      const float* __restrict__ query,
                                                      float* __restrict__ spart) {
    int b  = blockIdx.x;
    int n0 = b * SW_CHUNK;
    int t  = threadIdx.x;           // column c
    __shared__ float aw[HEADS][SW_CHUNK];

    aw[t >> 5][t & 31] = attn[(size_t)(t >> 5) * N_NODES + n0 + (t & 31)];
    __syncthreads();

    float acc[HEADS];
#pragma unroll
    for (int h = 0; h < HEADS; ++h) acc[h] = 0.f;

#pragma unroll 4
    for (int n = 0; n < SW_CHUNK; ++n) {
        float qv = query[(size_t)(n0 + n) * EDIM + t];
#pragma unroll
        for (int h = 0; h < HEADS; ++h)
            acc[h] = fmaf(aw[h][n], qv, acc[h]);
    }
#pragma unroll
    for (int h = 0; h < HEADS; ++h)
        spart[((size_t)b * HEADS + h) * EDIM + t] = acc[h];
}

// ---------------------------------------------------------------------------
// K4c: s[h][c] = sum_b spart[b][h][c]
// ---------------------------------------------------------------------------
__global__ __launch_bounds__(256) void sreduce_kernel(const float* __restrict__ spart,
                                                      float* __restrict__ s) {
    int h = blockIdx.x, c = threadIdx.x;
    float acc = 0.f;
    for (int b = 0; b < SW_BLOCKS; ++b)
        acc += spart[((size_t)b * HEADS + h) * EDIM + c];
    s[(size_t)h * EDIM + c] = acc;
}

// ---------------------------------------------------------------------------
// K5a: of[j] = b_in[512+j] + s[j>>5,:] . W_in[512+j,:]
// ---------------------------------------------------------------------------
__global__ __launch_bounds__(64) void gemv1_kernel(const float* __restrict__ s,
                                                   const float* __restrict__ W_in,
                                                   const float* __restrict__ b_in,
                                                   float* __restrict__ of) {
    int j = blockIdx.x, lane = threadIdx.x;
    const float4 w  = ((const float4*)(W_in + (size_t)(2 * EDIM + j) * EDIM))[lane];
    const float4 sv = ((const float4*)(s + (size_t)(j >> 5) * EDIM))[lane];
    float p = w.x * sv.x + w.y * sv.y + w.z * sv.z + w.w * sv.w;
    p += __shfl_xor(p, 1);  p += __shfl_xor(p, 2);  p += __shfl_xor(p, 4);
    p += __shfl_xor(p, 8);  p += __shfl_xor(p, 16); p += __shfl_xor(p, 32);
    if (lane == 0) of[j] = p + b_in[2 * EDIM + j];
}

// ---------------------------------------------------------------------------
// K5b: r[i] = b_out[i] + W_out[i,:] . of
// ---------------------------------------------------------------------------
__global__ __launch_bounds__(64) void gemv2_kernel(const float* __restrict__ of,
                                                   const float* __restrict__ W_out,
                                                   const float* __restrict__ b_out,
                                                   float* __restrict__ r) {
    int i = blockIdx.x, lane = threadIdx.x;
    const float4 w = ((const float4*)(W_out + (size_t)i * EDIM))[lane];
    const float4 v = ((const float4*)of)[lane];
    float p = w.x * v.x + w.y * v.y + w.z * v.z + w.w * v.w;
    p += __shfl_xor(p, 1);  p += __shfl_xor(p, 2);  p += __shfl_xor(p, 4);
    p += __shfl_xor(p, 8);  p += __shfl_xor(p, 16); p += __shfl_xor(p, 32);
    if (lane == 0) r[i] = p + b_out[i];
}

// ---------------------------------------------------------------------------
// K6: broadcast row r to all N rows of out.
// ---------------------------------------------------------------------------
__global__ __launch_bounds__(256) void bcast_kernel(const float* __restrict__ r,
                                                    float* __restrict__ out) {
    int idx = blockIdx.x * blockDim.x + threadIdx.x;
    const float4* r4 = (const float4*)r;
    ((float4*)out)[idx] = r4[idx & 63];
}

// ---------------------------------------------------------------------------
extern "C" void kernel_launch(void* const* d_in, const int* in_sizes, int n_in,
                              void* d_out, int out_size, void* d_ws, size_t ws_size,
                              hipStream_t stream) {
    const float* query     = (const float*)d_in[0];
    const int*   edge_idx  = (const int*)d_in[1];
    const float* attn_bias = (const float*)d_in[2];
    const float* W_in      = (const float*)d_in[3];
    const float* b_in      = (const float*)d_in[4];
    const float* W_out     = (const float*)d_in[5];
    const float* b_out     = (const float*)d_in[6];
    float* out = (float*)d_out;
    float* ws  = (float*)d_ws;

    unsigned short* q_bf  = (unsigned short*)ws;          // 2,097,152 us (=1,048,576 f)
    unsigned short* qbf_in = q_bf + 2097152;              // 2,097,152 us
    unsigned short* Wall  = qbf_in + 2097152;             //    73,728 us (=36,864 f)
    float* khs        = ws + 1048576 * 2 + 36864;         //   262,144
    float* bksum      = khs + 262144;                     //        64
    float* r          = bksum + 64;                       //       256
    float* of         = r + 256;                          //       256
    float* s          = of + 256;                         //     2,048
    float* spart      = s + 2048;                         //   524,288
    int*   counts     = (int*)(spart + 524288);           //     8,192 (zeroed)
    int*   cursor     = counts + 8192;                    //     8,192
    int*   offsets    = cursor + 8192;                    //     8,200
    int*   sorted_dst = offsets + 8200;                   //   262,144
    uint4* sorted_bias = (uint4*)(sorted_dst + 262144);   //   262,144 uint4
    float* col        = (float*)(sorted_bias + 262144);   //    65,536
    float* attn       = col + 65536;                      //    65,536

    zero_kernel<<<32, 256, 0, stream>>>(counts);
    convq_kernel<<<N_NODES * EDIM / 4 / 256, 256, 0, stream>>>(query, qbf_in);
    prepw_kernel<<<288, 256, 0, stream>>>(W_in, b_in, Wall, bksum);

    qk_mfma<<<2304, 256, 0, stream>>>(qbf_in, Wall, b_in, bksum, q_bf, khs);

    hist_kernel<<<NEDGE / 256, 256, 0, stream>>>(edge_idx, counts);
    scan_kernel<<<1, 256, 0, stream>>>(counts, offsets, cursor);
    scatter_kernel<<<NEDGE / 256, 256, 0, stream>>>(edge_idx, attn_bias, cursor,
                                                    sorted_dst, sorted_bias);
    src_edge_kernel<<<N_NODES / 4, 256, 0, stream>>>(q_bf, khs, sorted_dst,
                                                     (const unsigned short*)sorted_bias,
                                                     offsets, col);

    softmax_kernel<<<HEADS, 256, 0, stream>>>(col, offsets, attn);

    sweight_kernel<<<SW_BLOCKS, 256, 0, stream>>>(attn, query, spart);
    sreduce_kernel<<<HEADS, 256, 0, stream>>>(spart, s);

    gemv1_kernel<<<EDIM, 64, 0, stream>>>(s, W_in, b_in, of);
    gemv2_kernel<<<EDIM, 64, 0, stream>>>(of, W_out, b_out, r);

    bcast_kernel<<<(N_NODES * EDIM / 4) / 256, 256, 0, stream>>>(r, out);
}

// Round 7
// 129.284 us; speedup vs baseline: 3.3979x; 1.2415x over previous
//
#include <hip/hip_runtime.h>
#include <hip/hip_bf16.h>
#include <math.h>

#define N_NODES 8192
#define EDIM    256
#define HEADS   8
#define HDIM    32
#define NEDGE   262144
#define SCALING 0.17677669529663687f   // 1/sqrt(32)
#define SW_CHUNK 32
#define SW_BLOCKS (N_NODES / SW_CHUNK)   // 256

typedef __attribute__((ext_vector_type(8))) short bf16x8;
typedef __attribute__((ext_vector_type(4))) float f32x4;

__device__ __forceinline__ float bf2f(unsigned short u) {
    return __uint_as_float(((unsigned)u) << 16);
}
__device__ __forceinline__ unsigned short f2bf(float f) {
    __hip_bfloat16 h = __float2bfloat16(f);
    return *reinterpret_cast<unsigned short*>(&h);
}
__device__ __forceinline__ float4 cvt4(ushort4 u) {
    return make_float4(bf2f(u.x), bf2f(u.y), bf2f(u.z), bf2f(u.w));
}

// ---------------------------------------------------------------------------
// K1: prep = zero counts (blocks 0..31) + Wall/bksum build (blocks 32..319)
//   Wall[288][256] bf16: rows 0..255 = W_in[j]; rows 256..287 = sum_h Wk_h
// ---------------------------------------------------------------------------
__global__ __launch_bounds__(256) void prep_kernel(const float* __restrict__ W_in,
                                                   const float* __restrict__ b_in,
                                                   unsigned short* __restrict__ Wall,
                                                   float* __restrict__ bksum,
                                                   int* __restrict__ counts) {
    int b = blockIdx.x;
    int c = threadIdx.x;
    if (b < 32) { counts[b * 256 + c] = 0; return; }
    int row = b - 32;                 // 0..287
    if (row < 256) {
        Wall[(size_t)row * EDIM + c] = f2bf(W_in[(size_t)row * EDIM + c]);
    } else {
        int d = row - 256;
        float s = 0.f;
        for (int h = 0; h < HEADS; ++h)
            s += W_in[(size_t)(EDIM + h * HDIM + d) * EDIM + c];
        Wall[(size_t)row * EDIM + c] = f2bf(s);
        if (c == 0) {
            float bs = 0.f;
            for (int h = 0; h < HEADS; ++h)
                bs += b_in[EDIM + h * HDIM + d];
            bksum[d] = bs;
        }
    }
}

// ---------------------------------------------------------------------------
// K2: qk MFMA GEMM (blocks 0..255; 32 rows/block, A staged in LDS with XOR
//     swizzle) + src histogram (blocks 256..1279).
//   out[n,j] = query[n,:].Wall[j,:]; j<256 -> q_bf (bf16, +b, *SCALING);
//   j>=256 -> khs f32 (+bksum).
// Sub-tile split: wave w -> rt=w&1 (16-row half), tc = (w>>1)+2*i, i=0..8.
// ---------------------------------------------------------------------------
__global__ __launch_bounds__(256) void qk_hist_kernel(const float* __restrict__ query,
                                                      const unsigned short* __restrict__ Wall,
                                                      const float* __restrict__ b_in,
                                                      const float* __restrict__ bksum,
                                                      const int* __restrict__ edge_index,
                                                      int* __restrict__ counts,
                                                      unsigned short* __restrict__ q_bf,
                                                      float* __restrict__ khs) {
    if (blockIdx.x >= 256) {
        int e = (blockIdx.x - 256) * 256 + threadIdx.x;
        atomicAdd(counts + edge_index[e], 1);
        return;
    }
    __shared__ unsigned short A_lds[32][256];   // 16 KB, chunk-swizzled

    int t = threadIdx.x;
    int row0 = blockIdx.x * 32;

    // --- stage A: thread t -> row t>>3, four 8-elem chunks (t&7)*4.. ---
    {
        int srow = t >> 3;
        int c0   = (t & 7) * 4;
        const float* qrow = query + (size_t)(row0 + srow) * EDIM;
#pragma unroll
        for (int c = 0; c < 4; ++c) {
            int chunk = c0 + c;                       // 0..31 (8 bf16 each)
            float4 f0 = *(const float4*)(qrow + chunk * 8);
            float4 f1 = *(const float4*)(qrow + chunk * 8 + 4);
            ushort4 u0 = make_ushort4(f2bf(f0.x), f2bf(f0.y), f2bf(f0.z), f2bf(f0.w));
            ushort4 u1 = make_ushort4(f2bf(f1.x), f2bf(f1.y), f2bf(f1.z), f2bf(f1.w));
            int pch = chunk ^ (srow & 7);
            *(ushort4*)(&A_lds[srow][pch * 8])     = u0;
            *(ushort4*)(&A_lds[srow][pch * 8 + 4]) = u1;
        }
    }
    __syncthreads();

    int w = t >> 6, lane = t & 63;
    int rt  = w & 1;
    int tcb = w >> 1;
    int r  = lane & 15;
    int kc = lane >> 4;                  // 0..3
    int arow = rt * 16 + r;
    int swz  = (arow & 7);

#pragma unroll
    for (int i = 0; i < 9; ++i) {
        int tc  = tcb + 2 * i;           // 0..17
        int col = tc * 16 + r;
        const bf16x8* brow = (const bf16x8*)(Wall + (size_t)col * EDIM);
        f32x4 acc = {0.f, 0.f, 0.f, 0.f};
#pragma unroll
        for (int ks = 0; ks < 8; ++ks) {
            int chunk = ks * 4 + kc;
            bf16x8 a = *(const bf16x8*)(&A_lds[arow][(chunk ^ swz) * 8]);
            bf16x8 bb = brow[chunk];
            acc = __builtin_amdgcn_mfma_f32_16x16x32_bf16(a, bb, acc, 0, 0, 0);
        }
        // D layout: node = row-base + (lane>>4)*4 + reg, feat = col
        if (col < 256) {
            float bias = b_in[col];
#pragma unroll
            for (int qi = 0; qi < 4; ++qi) {
                int node = row0 + rt * 16 + (lane >> 4) * 4 + qi;
                q_bf[(size_t)node * EDIM + col] = f2bf((acc[qi] + bias) * SCALING);
            }
        } else {
            int d = col - 256;
            float bias = bksum[d];
#pragma unroll
            for (int qi = 0; qi < 4; ++qi) {
                int node = row0 + rt * 16 + (lane >> 4) * 4 + qi;
                khs[(size_t)node * HDIM + d] = acc[qi] + bias;
            }
        }
    }
}

// ---------------------------------------------------------------------------
// K3: exclusive prefix scan of counts[8192] -> offsets[8193], cursor copy
// ---------------------------------------------------------------------------
__global__ __launch_bounds__(256) void scan_kernel(const int* __restrict__ counts,
                                                   int* __restrict__ offsets,
                                                   int* __restrict__ cursor) {
    __shared__ int part[256];
    int t = threadIdx.x;
    int base = t * 32;
    int local[32];
    int s = 0;
#pragma unroll
    for (int i = 0; i < 32; ++i) { local[i] = counts[base + i]; s += local[i]; }
    part[t] = s;
    __syncthreads();
    for (int st = 1; st < 256; st <<= 1) {
        int v = (t >= st) ? part[t - st] : 0;
        __syncthreads();
        part[t] += v;
        __syncthreads();
    }
    int off = part[t] - s;   // exclusive
#pragma unroll
    for (int i = 0; i < 32; ++i) {
        offsets[base + i] = off;
        cursor[base + i]  = off;
        off += local[i];
    }
    if (t == 255) offsets[8192] = off;
}

// ---------------------------------------------------------------------------
// K4: scatter edges into src-grouped order; packed bf16x8 bias records.
// ---------------------------------------------------------------------------
__global__ __launch_bounds__(256) void scatter_kernel(const int* __restrict__ edge_index,
                                                      const float* __restrict__ bias,
                                                      int* __restrict__ cursor,
                                                      int* __restrict__ sorted_dst,
                                                      uint4* __restrict__ sorted_bias) {
    int e = blockIdx.x * 256 + threadIdx.x;
    int src = edge_index[e];
    int dst = edge_index[NEDGE + e];
    int pos = atomicAdd(cursor + src, 1);
    sorted_dst[pos] = dst;
    unsigned b0 = f2bf(bias[0 * NEDGE + e]) | ((unsigned)f2bf(bias[1 * NEDGE + e]) << 16);
    unsigned b1 = f2bf(bias[2 * NEDGE + e]) | ((unsigned)f2bf(bias[3 * NEDGE + e]) << 16);
    unsigned b2 = f2bf(bias[4 * NEDGE + e]) | ((unsigned)f2bf(bias[5 * NEDGE + e]) << 16);
    unsigned b3 = f2bf(bias[6 * NEDGE + e]) | ((unsigned)f2bf(bias[7 * NEDGE + e]) << 16);
    sorted_bias[pos] = make_uint4(b0, b1, b2, b3);
}

// ---------------------------------------------------------------------------
// K5: per-src segment reduction, NO atomics.
//   col[h,j] = (sum_{e:src=j} q[dst_e,h,:]).khs[j,:] + sum_{e:src=j} bias[h,e]
// ---------------------------------------------------------------------------
__global__ __launch_bounds__(256) void src_edge_kernel(const unsigned short* __restrict__ q_bf,
                                                       const float* __restrict__ khs,
                                                       const int* __restrict__ sorted_dst,
                                                       const unsigned short* __restrict__ sorted_bias,
                                                       const int* __restrict__ offsets,
                                                       float* __restrict__ col) {
    int wslot = threadIdx.x >> 6;
    int lane  = threadIdx.x & 63;
    int j     = blockIdx.x * 4 + wslot;
    int start = offsets[j], end = offsets[j + 1];
    if (start == end) return;   // untouched node: col never read

    int sub = lane & 7, grp = lane >> 3;
    const ushort4* q4 = (const ushort4*)q_bf;   // row = 64 ushort4

    float4 a0 = make_float4(0.f, 0.f, 0.f, 0.f);
    float4 a1 = make_float4(0.f, 0.f, 0.f, 0.f);
    float4 a2 = make_float4(0.f, 0.f, 0.f, 0.f);
    float4 a3 = make_float4(0.f, 0.f, 0.f, 0.f);
    int p = start;
    for (; p + 3 < end; p += 4) {
        ushort4 u0 = q4[(size_t)sorted_dst[p + 0] * 64 + lane];
        ushort4 u1 = q4[(size_t)sorted_dst[p + 1] * 64 + lane];
        ushort4 u2 = q4[(size_t)sorted_dst[p + 2] * 64 + lane];
        ushort4 u3 = q4[(size_t)sorted_dst[p + 3] * 64 + lane];
        float4 v0 = cvt4(u0), v1 = cvt4(u1), v2 = cvt4(u2), v3 = cvt4(u3);
        a0.x += v0.x; a0.y += v0.y; a0.z += v0.z; a0.w += v0.w;
        a1.x += v1.x; a1.y += v1.y; a1.z += v1.z; a1.w += v1.w;
        a2.x += v2.x; a2.y += v2.y; a2.z += v2.z; a2.w += v2.w;
        a3.x += v3.x; a3.y += v3.y; a3.z += v3.z; a3.w += v3.w;
    }
    for (; p < end; ++p) {
        float4 v0 = cvt4(q4[(size_t)sorted_dst[p] * 64 + lane]);
        a0.x += v0.x; a0.y += v0.y; a0.z += v0.z; a0.w += v0.w;
    }
    a0.x += a1.x + a2.x + a3.x;
    a0.y += a1.y + a2.y + a3.y;
    a0.z += a1.z + a2.z + a3.z;
    a0.w += a1.w + a2.w + a3.w;

    float ab = 0.f;
    for (int pb = start + grp; pb < end; pb += 8)
        ab += bf2f(sorted_bias[(size_t)pb * 8 + sub]);
    ab += __shfl_xor(ab, 8);
    ab += __shfl_xor(ab, 16);
    ab += __shfl_xor(ab, 32);          // every lane: bias sum for head=sub

    const float4 kv = *(const float4*)(khs + (size_t)j * HDIM + sub * 4);
    float pd = a0.x * kv.x + a0.y * kv.y + a0.z * kv.z + a0.w * kv.w;
    pd += __shfl_xor(pd, 1);
    pd += __shfl_xor(pd, 2);
    pd += __shfl_xor(pd, 4);           // every lane of 8-group: dot for head=grp

    if (grp == sub)
        col[(size_t)grp * N_NODES + j] = pd + ab;
}

// ---------------------------------------------------------------------------
// K6: per-head softmax stats only: sminfo[2h] = max, sminfo[2h+1] = 1/sum
// ---------------------------------------------------------------------------
__global__ __launch_bounds__(256) void smstats_kernel(const float* __restrict__ col,
                                                      const int* __restrict__ offsets,
                                                      float* __restrict__ sminfo) {
    int h = blockIdx.x;
    const float* c = col + (size_t)h * N_NODES;
    __shared__ float red[256];
    int t = threadIdx.x;

    float m = -INFINITY;
    for (int n = t; n < N_NODES; n += 256)
        if (offsets[n + 1] > offsets[n]) m = fmaxf(m, c[n]);
    red[t] = m; __syncthreads();
    for (int st = 128; st; st >>= 1) {
        if (t < st) red[t] = fmaxf(red[t], red[t + st]);
        __syncthreads();
    }
    m = red[0]; __syncthreads();

    float sum = 0.f;
    for (int n = t; n < N_NODES; n += 256)
        if (offsets[n + 1] > offsets[n]) sum += expf(c[n] - m);
    red[t] = sum; __syncthreads();
    for (int st = 128; st; st >>= 1) {
        if (t < st) red[t] += red[t + st];
        __syncthreads();
    }
    if (t == 0) { sminfo[2 * h] = m; sminfo[2 * h + 1] = 1.f / red[0]; }
}

// ---------------------------------------------------------------------------
// K7: partials with softmax normalize folded in:
//   spart[b][h][c] = sum_{n in chunk} exp(col[h,n]-m)*inv * query[n,c]
// ---------------------------------------------------------------------------
__global__ __launch_bounds__(256) void sweight_kernel(const float* __restrict__ col,
                                                      const int* __restrict__ offsets,
                                                      const float* __restrict__ sminfo,
                                                      const float* __restrict__ query,
                                                      float* __restrict__ spart) {
    int b  = blockIdx.x;
    int n0 = b * SW_CHUNK;
    int t  = threadIdx.x;           // column c
    __shared__ float aw[HEADS][SW_CHUNK];

    {
        int hh = t >> 5, nn = t & 31;
        int n  = n0 + nn;
        bool touched = offsets[n + 1] > offsets[n];
        float m   = sminfo[2 * hh];
        float inv = sminfo[2 * hh + 1];
        aw[hh][nn] = touched ? expf(col[(size_t)hh * N_NODES + n] - m) * inv : 0.f;
    }
    __syncthreads();

    float acc[HEADS];
#pragma unroll
    for (int h = 0; h < HEADS; ++h) acc[h] = 0.f;

#pragma unroll 4
    for (int n = 0; n < SW_CHUNK; ++n) {
        float qv = query[(size_t)(n0 + n) * EDIM + t];
#pragma unroll
        for (int h = 0; h < HEADS; ++h)
            acc[h] = fmaf(aw[h][n], qv, acc[h]);
    }
#pragma unroll
    for (int h = 0; h < HEADS; ++h)
        spart[((size_t)b * HEADS + h) * EDIM + t] = acc[h];
}

// ---------------------------------------------------------------------------
// K8: s[h][c] = sum_b spart[b][h][c]
// ---------------------------------------------------------------------------
__global__ __launch_bounds__(256) void sreduce_kernel(const float* __restrict__ spart,
                                                      float* __restrict__ s) {
    int h = blockIdx.x, c = threadIdx.x;
    float acc = 0.f;
    for (int b = 0; b < SW_BLOCKS; ++b)
        acc += spart[((size_t)b * HEADS + h) * EDIM + c];
    s[(size_t)h * EDIM + c] = acc;
}

// ---------------------------------------------------------------------------
// K9: of[j] = b_in[512+j] + s[j>>5,:] . W_in[512+j,:]
// ---------------------------------------------------------------------------
__global__ __launch_bounds__(64) void gemv1_kernel(const float* __restrict__ s,
                                                   const float* __restrict__ W_in,
                                                   const float* __restrict__ b_in,
                                                   float* __restrict__ of) {
    int j = blockIdx.x, lane = threadIdx.x;
    const float4 w  = ((const float4*)(W_in + (size_t)(2 * EDIM + j) * EDIM))[lane];
    const float4 sv = ((const float4*)(s + (size_t)(j >> 5) * EDIM))[lane];
    float p = w.x * sv.x + w.y * sv.y + w.z * sv.z + w.w * sv.w;
    p += __shfl_xor(p, 1);  p += __shfl_xor(p, 2);  p += __shfl_xor(p, 4);
    p += __shfl_xor(p, 8);  p += __shfl_xor(p, 16); p += __shfl_xor(p, 32);
    if (lane == 0) of[j] = p + b_in[2 * EDIM + j];
}

// ---------------------------------------------------------------------------
// K10: r[i] = b_out[i] + W_out[i,:] . of
// ---------------------------------------------------------------------------
__global__ __launch_bounds__(64) void gemv2_kernel(const float* __restrict__ of,
                                                   const float* __restrict__ W_out,
                                                   const float* __restrict__ b_out,
                                                   float* __restrict__ r) {
    int i = blockIdx.x, lane = threadIdx.x;
    const float4 w = ((const float4*)(W_out + (size_t)i * EDIM))[lane];
    const float4 v = ((const float4*)of)[lane];
    float p = w.x * v.x + w.y * v.y + w.z * v.z + w.w * v.w;
    p += __shfl_xor(p, 1);  p += __shfl_xor(p, 2);  p += __shfl_xor(p, 4);
    p += __shfl_xor(p, 8);  p += __shfl_xor(p, 16); p += __shfl_xor(p, 32);
    if (lane == 0) r[i] = p + b_out[i];
}

// ---------------------------------------------------------------------------
// K11: broadcast row r to all N rows of out.
// ---------------------------------------------------------------------------
__global__ __launch_bounds__(256) void bcast_kernel(const float* __restrict__ r,
                                                    float* __restrict__ out) {
    int idx = blockIdx.x * blockDim.x + threadIdx.x;
    const float4* r4 = (const float4*)r;
    ((float4*)out)[idx] = r4[idx & 63];
}

// ---------------------------------------------------------------------------
extern "C" void kernel_launch(void* const* d_in, const int* in_sizes, int n_in,
                              void* d_out, int out_size, void* d_ws, size_t ws_size,
                              hipStream_t stream) {
    const float* query     = (const float*)d_in[0];
    const int*   edge_idx  = (const int*)d_in[1];
    const float* attn_bias = (const float*)d_in[2];
    const float* W_in      = (const float*)d_in[3];
    const float* b_in      = (const float*)d_in[4];
    const float* W_out     = (const float*)d_in[5];
    const float* b_out     = (const float*)d_in[6];
    float* out = (float*)d_out;
    float* ws  = (float*)d_ws;

    unsigned short* q_bf = (unsigned short*)ws;          // 2,097,152 us (1,048,576 f)
    unsigned short* Wall = (unsigned short*)(ws + 1048576); // 73,728 us (36,864 f)
    float* khs        = ws + 1048576 + 36864;            //   262,144
    float* bksum      = khs + 262144;                    //        64
    float* sminfo     = bksum + 64;                      //        64 (16 used)
    float* r          = sminfo + 64;                     //       256
    float* of         = r + 256;                         //       256
    float* s          = of + 256;                        //     2,048
    float* spart      = s + 2048;                        //   524,288
    int*   counts     = (int*)(spart + 524288);          //     8,192
    int*   cursor     = counts + 8192;                   //     8,192
    int*   offsets    = cursor + 8192;                   //     8,200
    int*   sorted_dst = offsets + 8200;                  //   262,144
    uint4* sorted_bias = (uint4*)(sorted_dst + 262144);  //   262,144 uint4
    float* col        = (float*)(sorted_bias + 262144);  //    65,536

    prep_kernel<<<320, 256, 0, stream>>>(W_in, b_in, Wall, bksum, counts);

    qk_hist_kernel<<<1280, 256, 0, stream>>>(query, Wall, b_in, bksum,
                                             edge_idx, counts, q_bf, khs);

    scan_kernel<<<1, 256, 0, stream>>>(counts, offsets, cursor);
    scatter_kernel<<<NEDGE / 256, 256, 0, stream>>>(edge_idx, attn_bias, cursor,
                                                    sorted_dst, sorted_bias);
    src_edge_kernel<<<N_NODES / 4, 256, 0, stream>>>(q_bf, khs, sorted_dst,
                                                     (const unsigned short*)sorted_bias,
                                                     offsets, col);

    smstats_kernel<<<HEADS, 256, 0, stream>>>(col, offsets, sminfo);

    sweight_kernel<<<SW_BLOCKS, 256, 0, stream>>>(col, offsets, sminfo, query, spart);
    sreduce_kernel<<<HEADS, 256, 0, stream>>>(spart, s);

    gemv1_kernel<<<EDIM, 64, 0, stream>>>(s, W_in, b_in, of);
    gemv2_kernel<<<EDIM, 64, 0, stream>>>(of, W_out, b_out, r);

    bcast_kernel<<<(N_NODES * EDIM / 4) / 256, 256, 0, stream>>>(r, out);
}